// Round 15
// baseline (120.626 us; speedup 1.0000x reference)
//
#include <hip/hip_runtime.h>
#include <hip/hip_fp16.h>
#include <math.h>

#define BB 8        // batch count (fixed by problem instance)
#define NB 128      // counting-sort blocks (chunk owners)
#define NBINS 10016 // padded bin count; fast path requires N <= NBINS
#define FPAD 14     // fsh row stride in dwords (56B: 8B-aligned, bank-spread)

typedef float f32x2 __attribute__((ext_vector_type(2)));
typedef float f32x4 __attribute__((ext_vector_type(4)));
typedef _Float16 h16x4 __attribute__((ext_vector_type(4)));

__device__ __forceinline__ float sigmoidf_(float v) {
    return __builtin_amdgcn_rcpf(1.0f + __expf(-v));
}
__device__ __forceinline__ float sigs_(float d) {   // pre-activation scaled by log2(e)
    return __builtin_amdgcn_rcpf(1.0f + __builtin_amdgcn_exp2f(-d));
}
__device__ __forceinline__ unsigned pkh2_(float a, float b) {
    __half2 h = __floats2half2_rn(a, b);
    return *reinterpret_cast<unsigned*>(&h);
}

// ---- K1 prep: ea stats + xT transpose + per-block LDS histogram -> cnt2 ----
__global__ __launch_bounds__(256) void prep_kernel(
    const float* __restrict__ ea, const int* __restrict__ ei,
    const float* __restrict__ x, float* __restrict__ xT,
    unsigned short* __restrict__ cnt2, double* __restrict__ acc,
    int N, int E, int full)
{
    __shared__ unsigned hist[NBINS];
    __shared__ double sh[4][256];
    int tid = threadIdx.x;
    int blk = blockIdx.x;

    if (full) {
        for (int b = tid; b < NBINS; b += 256) hist[b] = 0u;
    }

    double s0 = 0, q0 = 0, s1 = 0, q1 = 0;
    for (int i = blk * 256 + tid; i < E; i += NB * 256) {
        float a = ea[2 * i];
        float b = ea[2 * i + 1];
        s0 += (double)a; q0 += (double)a * (double)a;
        s1 += (double)b; q1 += (double)b * (double)b;
    }

    if (full) {
        int xtotal = N * BB * 3;
        for (int idx = blk * 256 + tid; idx < xtotal; idx += NB * 256) {
            int c = idx % 3;
            int rest = idx / 3;
            int n = rest % N;
            int b = rest / N;
            xT[n * 24 + b * 3 + c] = x[idx];
        }
        __syncthreads();
        int chunk = (E + NB - 1) / NB;
        int s = blk * chunk;
        int epd = min(E, s + chunk);
        for (int e = s + tid; e < epd; e += 256) {
            atomicAdd(&hist[ei[E + e]], 1u);   // tgt (+g)
            atomicAdd(&hist[ei[e]], 1u);       // src (-g)
        }
        __syncthreads();
        unsigned short* row = cnt2 + (size_t)blk * NBINS;
        for (int b = tid; b < NBINS; b += 256)
            row[b] = (unsigned short)hist[b];
    }

    sh[0][tid] = s0; sh[1][tid] = q0; sh[2][tid] = s1; sh[3][tid] = q1;
    __syncthreads();
    for (int off = 128; off > 0; off >>= 1) {
        if (tid < off) {
            sh[0][tid] += sh[0][tid + off];
            sh[1][tid] += sh[1][tid + off];
            sh[2][tid] += sh[2][tid + off];
            sh[3][tid] += sh[3][tid + off];
        }
        __syncthreads();
    }
    if (tid == 0) {
        atomicAdd(&acc[0], sh[0][0]);
        atomicAdd(&acc[1], sh[1][0]);
        atomicAdd(&acc[2], sh[2][0]);
        atomicAdd(&acc[3], sh[3][0]);
    }
}

// ---- K2 base: per-bin exclusive prefix over blocks (in-place) + totals ----
__global__ __launch_bounds__(256) void base_kernel(unsigned short* __restrict__ cnt2,
                                                   int* __restrict__ tot) {
    int bin = blockIdx.x * 256 + threadIdx.x;
    if (bin >= NBINS) return;
    unsigned run = 0;
    #pragma unroll 8
    for (int blk = 0; blk < NB; blk++) {
        size_t idx = (size_t)blk * NBINS + bin;
        unsigned v = cnt2[idx];
        cnt2[idx] = (unsigned short)run;
        run += v;
    }
    tot[bin] = (int)run;
}

// ---- K3 scan: exclusive scan over node totals + stats finalize ----
__global__ __launch_bounds__(1024) void scan_kernel(const int* __restrict__ tot,
                                                    int* __restrict__ off, int N,
                                                    const double* __restrict__ acc, int E,
                                                    float* __restrict__ stats) {
    if (threadIdx.x == 0) {
        double s0 = acc[0], q0 = acc[1], s1 = acc[2], q1 = acc[3];
        double v0 = (q0 - s0 * s0 / E) / (double)(E - 1);
        double v1 = (q1 - s1 * s1 / E) / (double)(E - 1);
        stats[0] = (float)(s0 / E);
        stats[1] = (float)(1.0 / sqrt(v0));
        stats[2] = (float)(s1 / E);
        stats[3] = (float)(1.0 / sqrt(v1));
    }
    __shared__ int sh[1024];
    int t = threadIdx.x;
    int chunk = (N + 1023) >> 10;
    int lo = t * chunk;
    int hi = lo + chunk; if (hi > N) hi = N;
    int s = 0;
    for (int i = lo; i < hi; i++) s += tot[i];
    sh[t] = s;
    __syncthreads();
    for (int d = 1; d < 1024; d <<= 1) {
        int v = (t >= d) ? sh[t - d] : 0;
        __syncthreads();
        sh[t] += v;
        __syncthreads();
    }
    int run = (t == 0) ? 0 : sh[t - 1];
    for (int i = lo; i < hi; i++) {
        off[i] = run;
        run += tot[i];
    }
    if (t == 1023) off[N] = sh[1023];
}

// ---- K4 ranklist: recompute local ranks in LDS, emit CSR list directly ----
__global__ __launch_bounds__(256) void ranklist_kernel(
    const int* __restrict__ ei, int E,
    const unsigned short* __restrict__ cnt2,
    const int* __restrict__ off, int* __restrict__ list)
{
    __shared__ unsigned hist[NBINS];
    int tid = threadIdx.x;
    int blk = blockIdx.x;
    for (int b = tid; b < NBINS; b += 256) hist[b] = 0u;
    __syncthreads();

    int chunk = (E + NB - 1) / NB;
    int s = blk * chunk;
    int epd = min(E, s + chunk);
    const unsigned short* row = cnt2 + (size_t)blk * NBINS;
    for (int e = s + tid; e < epd; e += 256) {
        int tgt = ei[E + e];
        int src = ei[e];
        unsigned lt = atomicAdd(&hist[tgt], 1u);
        unsigned ls = atomicAdd(&hist[src], 1u);
        list[off[tgt] + (int)row[tgt] + (int)lt] = e;
        list[off[src] + (int)row[src] + (int)ls] = e | 0x80000000;
    }
}

// ---- K5: MFMA edge MLP (grid-stride, 2048 blocks = 8/CU exactly) ----
// Per wave-step: 8 edges x 8 batches = 64 (e,b) pairs -> f16 LDS stash
// (FPAD-dword rows for bank spread) -> 4 MFMA tiles of 16 cols.
// NB: every LDS dword B1 reads (fp[0..7]) MUST be initialized — 0 x NaN = NaN.
__global__ __launch_bounds__(256) void edge_mlp_mfma_kernel(
    const float* __restrict__ xT, const int* __restrict__ ei,
    const float* __restrict__ ea,
    const float* __restrict__ wmean, const float* __restrict__ wstd,
    const float* __restrict__ W1, const float* __restrict__ b1,
    const float* __restrict__ W2, const float* __restrict__ b2,
    const float* __restrict__ W3,
    const double* __restrict__ acc,
    uint2* __restrict__ gbuf,
    int N, int E)
{
    __shared__ unsigned fsh[4][64][FPAD];

    int lane = threadIdx.x & 63;
    int wave = threadIdx.x >> 6;
    int g = lane >> 4;        // k-group / row-group
    int arow = lane & 15;     // A row / D col

    const float LOG2E = 1.44269504088896340736f;

    // derive ea stats from acc (wave-uniform, once)
    double as0 = acc[0], aq0 = acc[1], as1 = acc[2], aq1 = acc[3];
    double v0 = (aq0 - as0 * as0 / E) / (double)(E - 1);
    double v1 = (aq1 - as1 * as1 / E) / (double)(E - 1);
    float st0 = (float)(as0 / E);
    float st1 = (float)(1.0 / sqrt(v0));
    float st2 = (float)(as1 / E);
    float st3 = (float)(1.0 / sqrt(v1));

    // preload weight fragments (constant across steps)
    h16x4 A1, A2a, A2b, A3a, A3b;
    #pragma unroll
    for (int j = 0; j < 4; j++) {
        int k = 4 * g + j;
        A1[j]  = (_Float16)((k < 9) ? W1[k * 16 + arow] * LOG2E : 0.0f);
        A2a[j] = (_Float16)(W2[k * 30 + arow] * LOG2E);
        A2b[j] = (_Float16)((arow < 14) ? W2[k * 30 + 16 + arow] * LOG2E : 0.0f);
        A3a[j] = (_Float16)((arow < 3) ? W3[k * 3 + arow] : 0.0f);
        int k2 = 16 + k;
        A3b[j] = (_Float16)((arow < 3 && k2 < 30) ? W3[k2 * 3 + arow] : 0.0f);
    }
    f32x4 C1, C2a, C2b;
    #pragma unroll
    for (int r = 0; r < 4; r++) {
        int row = 4 * g + r;
        C1[r]  = b1[row] * LOG2E;
        C2a[r] = b2[row] * LOG2E;
        C2b[r] = (row < 14) ? b2[16 + row] * LOG2E : 0.0f;
    }

    float wm0 = wmean[0], wm1 = wmean[1];
    float wsd0 = wstd[0], wsd1 = wstd[1];

    int e_loc = lane >> 3;    // 0..7 : edge within step
    int bb = lane & 7;        // 0..7 : batch

    // grid-stride over 32-edge groups (4 waves x 8 edges per block-step)
    for (int grp = blockIdx.x; grp * 32 < E; grp += gridDim.x) {
        int ebase = grp * 32 + wave * 8;
        if (ebase >= E) continue;

        int e = ebase + e_loc;
        int esafe = (e < E) ? e : (E - 1);
        int src = ei[esafe];
        int tgt = ei[E + esafe];
        float dist = ea[2 * esafe];
        float cdir = ea[2 * esafe + 1];

        const float* xs = xT + src * 24 + bb * 3;
        const float* xt = xT + tgt * 24 + bb * 3;
        float s0 = xs[0], s1 = xs[1], s2 = xs[2];
        float t0 = xt[0], t1 = xt[1], t2 = xt[2];
        float ea0 = (dist - st0) * st1;
        float ea1 = (cdir - st2) * st3;
        float speed = fmaf(s1, wsd0, wm0);
        float direc = fmaf(s2, wsd1, wm1);
        float theta = fabsf(cdir - direc);
        float ew = fmaxf(0.0f, speed * __cosf(theta) * 3.0f * __builtin_amdgcn_rcpf(dist));

        // pack 9 feats to f16, stash in LDS; zero-fill through fp[7]
        unsigned* fp = &fsh[wave][lane][0];
        uint4 wv0, wv1;
        wv0.x = pkh2_(s0, s1); wv0.y = pkh2_(s2, t0);
        wv0.z = pkh2_(t1, t2); wv0.w = pkh2_(ea0, ea1);
        wv1.x = pkh2_(ew, 0.0f); wv1.y = 0u; wv1.z = 0u; wv1.w = 0u;
        *reinterpret_cast<uint4*>(fp) = wv0;
        *reinterpret_cast<uint4*>(fp + 4) = wv1;

        // MFMA phase: 4 tiles of 16 cols
        #pragma unroll
        for (int t = 0; t < 4; t++) {
            const unsigned* q = &fsh[wave][t * 16 + arow][0];
            union { uint2 u; h16x4 h; } b1u;
            b1u.u = *reinterpret_cast<const uint2*>(q + 2 * g);

            f32x4 D1 = __builtin_amdgcn_mfma_f32_16x16x16f16(A1, b1u.h, C1, 0, 0, 0);
            union { uint2 u; h16x4 h; } b2u;
            b2u.u.x = pkh2_(sigs_(D1[0]), sigs_(D1[1]));
            b2u.u.y = pkh2_(sigs_(D1[2]), sigs_(D1[3]));

            f32x4 D2a = __builtin_amdgcn_mfma_f32_16x16x16f16(A2a, b2u.h, C2a, 0, 0, 0);
            f32x4 D2b = __builtin_amdgcn_mfma_f32_16x16x16f16(A2b, b2u.h, C2b, 0, 0, 0);
            union { uint2 u; h16x4 h; } b3au, b3bu;
            b3au.u.x = pkh2_(sigs_(D2a[0]), sigs_(D2a[1]));
            b3au.u.y = pkh2_(sigs_(D2a[2]), sigs_(D2a[3]));
            b3bu.u.x = pkh2_(sigs_(D2b[0]), sigs_(D2b[1]));
            b3bu.u.y = pkh2_(sigs_(D2b[2]), sigs_(D2b[3]));

            f32x4 Z = {0.f, 0.f, 0.f, 0.f};
            f32x4 D3 = __builtin_amdgcn_mfma_f32_16x16x16f16(A3a, b3au.h, Z, 0, 0, 0);
            D3 = __builtin_amdgcn_mfma_f32_16x16x16f16(A3b, b3bu.h, D3, 0, 0, 0);

            if (g == 0) {
                int et = ebase + 2 * t + (arow >> 3);   // edge of this col
                int bt = arow & 7;                      // batch of this col
                if (et < E) {
                    uint2 wp;
                    wp.x = pkh2_(D3[0], D3[1]);
                    wp.y = pkh2_(D3[2], 0.0f);
                    gbuf[(size_t)et * BB + bt] = wp;    // 16 lanes -> 128B linear
                }
            }
        }
    }
}

// ---- K6: one wave per node; each lane consumes one full 64B edge-line ----
__global__ __launch_bounds__(256) void node_sum_kernel(
    const uint2* __restrict__ gbuf, const int* __restrict__ off,
    const int* __restrict__ list,
    const float* __restrict__ b3, float* __restrict__ out, int N)
{
    int node = blockIdx.x * 4 + (threadIdx.x >> 6);
    int lane = threadIdx.x & 63;
    if (node >= N) return;

    int o0 = off[node], o1 = off[node + 1];
    float a[BB][3];
    #pragma unroll
    for (int b = 0; b < BB; b++) { a[b][0] = 0.f; a[b][1] = 0.f; a[b][2] = 0.f; }

    for (int i = o0 + lane; i < o1; i += 64) {
        int entry = list[i];
        int e = entry & 0x7FFFFFFF;
        float sgn = (entry < 0) ? -1.0f : 1.0f;
        const uint4* gl = reinterpret_cast<const uint4*>(gbuf + (size_t)e * BB);
        uint4 q0 = gl[0], q1 = gl[1], q2 = gl[2], q3 = gl[3];

        #define ACC_(bi, u01, u2x) {                                              \
            float2 f01 = __half22float2(*reinterpret_cast<const __half2*>(&u01)); \
            float2 f2  = __half22float2(*reinterpret_cast<const __half2*>(&u2x)); \
            a[bi][0] = fmaf(sgn, f01.x, a[bi][0]);                                \
            a[bi][1] = fmaf(sgn, f01.y, a[bi][1]);                                \
            a[bi][2] = fmaf(sgn, f2.x,  a[bi][2]); }
        ACC_(0, q0.x, q0.y) ACC_(1, q0.z, q0.w)
        ACC_(2, q1.x, q1.y) ACC_(3, q1.z, q1.w)
        ACC_(4, q2.x, q2.y) ACC_(5, q2.z, q2.w)
        ACC_(6, q3.x, q3.y) ACC_(7, q3.z, q3.w)
        #undef ACC_
    }

    #pragma unroll
    for (int m = 32; m >= 1; m >>= 1) {
        #pragma unroll
        for (int b = 0; b < BB; b++) {
            a[b][0] += __shfl_xor(a[b][0], m);
            a[b][1] += __shfl_xor(a[b][1], m);
            a[b][2] += __shfl_xor(a[b][2], m);
        }
    }

    float bb0 = b3[0], bb1 = b3[1], bb2 = b3[2];
    #pragma unroll
    for (int b = 0; b < BB; b++) {
        if (lane == b) {
            float* o = out + ((size_t)b * N + node) * 3;
            o[0] = sigmoidf_(a[b][0] + bb0);
            o[1] = sigmoidf_(a[b][1] + bb1);
            o[2] = sigmoidf_(a[b][2] + bb2);
        }
    }
}

// ---- Fallback path (small ws or N > NBINS): scalar MLP + atomic scatter ----
__global__ void finalize_stats_kernel(const double* __restrict__ acc, int E,
                                      float* __restrict__ stats) {
    double s0 = acc[0], q0 = acc[1], s1 = acc[2], q1 = acc[3];
    double v0 = (q0 - s0 * s0 / E) / (double)(E - 1);
    double v1 = (q1 - s1 * s1 / E) / (double)(E - 1);
    stats[0] = (float)(s0 / E);
    stats[1] = (float)(1.0 / sqrt(v0));
    stats[2] = (float)(s1 / E);
    stats[3] = (float)(1.0 / sqrt(v1));
}

__device__ __forceinline__ void mlp_eval(
    const float feat[9],
    const float* __restrict__ W1, const float* __restrict__ b1,
    const float* __restrict__ W2, const float* __restrict__ b2,
    const float* __restrict__ W3,
    float& g0, float& g1, float& g2)
{
    const f32x2* W1p = (const f32x2*)W1;
    const f32x2* b1p = (const f32x2*)b1;
    f32x2 acc1[8];
    #pragma unroll
    for (int j = 0; j < 8; j++) acc1[j] = b1p[j];
    #pragma unroll
    for (int k = 0; k < 9; k++) {
        f32x2 fk2 = {feat[k], feat[k]};
        #pragma unroll
        for (int j = 0; j < 8; j++)
            acc1[j] = __builtin_elementwise_fma(fk2, W1p[k * 8 + j], acc1[j]);
    }
    float h1[16];
    #pragma unroll
    for (int j = 0; j < 8; j++) {
        h1[2 * j]     = sigmoidf_(acc1[j].x);
        h1[2 * j + 1] = sigmoidf_(acc1[j].y);
    }
    const f32x2* W2p = (const f32x2*)W2;
    const f32x2* b2p = (const f32x2*)b2;
    f32x2 acc2[15];
    #pragma unroll
    for (int k = 0; k < 15; k++) acc2[k] = b2p[k];
    #pragma unroll
    for (int j = 0; j < 16; j++) {
        f32x2 hj2 = {h1[j], h1[j]};
        #pragma unroll
        for (int k = 0; k < 15; k++)
            acc2[k] = __builtin_elementwise_fma(hj2, W2p[j * 15 + k], acc2[k]);
    }
    g0 = 0.f; g1 = 0.f; g2 = 0.f;
    #pragma unroll
    for (int k = 0; k < 15; k++) {
        float ha = sigmoidf_(acc2[k].x);
        float hb = sigmoidf_(acc2[k].y);
        int ka = 2 * k, kb = 2 * k + 1;
        g0 = fmaf(ha, W3[ka * 3 + 0], g0); g0 = fmaf(hb, W3[kb * 3 + 0], g0);
        g1 = fmaf(ha, W3[ka * 3 + 1], g1); g1 = fmaf(hb, W3[kb * 3 + 1], g1);
        g2 = fmaf(ha, W3[ka * 3 + 2], g2); g2 = fmaf(hb, W3[kb * 3 + 2], g2);
    }
}

__global__ __launch_bounds__(256) void edge_atomic_kernel(
    const float* __restrict__ x, const int* __restrict__ ei,
    const float* __restrict__ ea,
    const float* __restrict__ wmean, const float* __restrict__ wstd,
    const float* __restrict__ W1, const float* __restrict__ b1,
    const float* __restrict__ W2, const float* __restrict__ b2,
    const float* __restrict__ W3,
    const float* __restrict__ stats,
    float* __restrict__ out, int N, int E)
{
    int e = blockIdx.x * blockDim.x + threadIdx.x;
    if (e >= E) return;
    int src = ei[e];
    int tgt = ei[E + e];
    float dist = ea[2 * e];
    float cdir = ea[2 * e + 1];
    float ea0 = (dist - stats[0]) * stats[1];
    float ea1 = (cdir - stats[2]) * stats[3];

    for (int b = 0; b < BB; b++) {
        const float* xb = x + (size_t)b * N * 3;
        float s0 = xb[src * 3 + 0], s1 = xb[src * 3 + 1], s2 = xb[src * 3 + 2];
        float t0 = xb[tgt * 3 + 0], t1 = xb[tgt * 3 + 1], t2 = xb[tgt * 3 + 2];
        float speed = fmaf(s1, wstd[0], wmean[0]);
        float direc = fmaf(s2, wstd[1], wmean[1]);
        float theta = fabsf(cdir - direc);
        float ew = fmaxf(0.0f, speed * __cosf(theta) * 3.0f * __builtin_amdgcn_rcpf(dist));
        float feat[9] = {s0, s1, s2, t0, t1, t2, ea0, ea1, ew};
        float g0, g1, g2;
        mlp_eval(feat, W1, b1, W2, b2, W3, g0, g1, g2);
        float* ot = out + ((size_t)b * N + tgt) * 3;
        float* os = out + ((size_t)b * N + src) * 3;
        atomicAdd(&ot[0], g0);  atomicAdd(&ot[1], g1);  atomicAdd(&ot[2], g2);
        atomicAdd(&os[0], -g0); atomicAdd(&os[1], -g1); atomicAdd(&os[2], -g2);
    }
}

__global__ void output_kernel(float* __restrict__ out, const float* __restrict__ b3, int total) {
    int i = blockIdx.x * blockDim.x + threadIdx.x;
    if (i < total) out[i] = sigmoidf_(out[i] + b3[i % 3]);
}

extern "C" void kernel_launch(void* const* d_in, const int* in_sizes, int n_in,
                              void* d_out, int out_size, void* d_ws, size_t ws_size,
                              hipStream_t stream) {
    const float* x     = (const float*)d_in[0];
    const int*   ei    = (const int*)d_in[1];
    const float* ea    = (const float*)d_in[2];
    const float* wmean = (const float*)d_in[3];
    const float* wstd  = (const float*)d_in[4];
    const float* W1    = (const float*)d_in[5];
    const float* b1    = (const float*)d_in[6];
    const float* W2    = (const float*)d_in[7];
    const float* b2    = (const float*)d_in[8];
    const float* W3    = (const float*)d_in[9];
    const float* b3    = (const float*)d_in[10];

    int E = in_sizes[2] / 2;        // edge_attr is (E, 2)
    int N = in_sizes[0] / (BB * 3); // x is (B, N, 3)

    float* out = (float*)d_out;
    char* ws = (char*)d_ws;

    // layout: [acc 4 dbl][stats 4 f][tot NBINS][off N+1][list 2E][xT N*24 f][cnt2 NB*NBINS u16][gbuf E*8 uint2]
    double* acc   = (double*)ws;                     // 32 B
    float*  stats = (float*)(ws + 32);               // 16 B (+16 pad)
    int*    tot   = (int*)(ws + 64);                 // NBINS
    int*    off   = tot + NBINS;                     // N+1
    int*    list  = off + N + 1;                     // 2E

    size_t xtOff = 64 + sizeof(int) * ((size_t)NBINS + (N + 1) + 2 * (size_t)E);
    xtOff = (xtOff + 255) & ~(size_t)255;
    float* xT = (float*)(ws + xtOff);

    size_t c2Off = xtOff + (size_t)N * 24 * sizeof(float);
    c2Off = (c2Off + 255) & ~(size_t)255;
    unsigned short* cnt2 = (unsigned short*)(ws + c2Off);

    size_t gbOff = c2Off + (size_t)NB * NBINS * sizeof(unsigned short);
    gbOff = (gbOff + 255) & ~(size_t)255;
    uint2* gbuf = (uint2*)(ws + gbOff);
    size_t needed = gbOff + (size_t)E * BB * sizeof(uint2);

    int eblocks = (E + 255) / 256;
    int fastPath = (needed <= ws_size && N <= NBINS) ? 1 : 0;

    hipMemsetAsync(acc, 0, 32, stream);   // zero stats accumulator only

    if (fastPath) {
        prep_kernel<<<NB, 256, 0, stream>>>(ea, ei, x, xT, cnt2, acc, N, E, 1);
        base_kernel<<<(NBINS + 255) / 256, 256, 0, stream>>>(cnt2, tot);
        scan_kernel<<<1, 1024, 0, stream>>>(tot, off, N, acc, E, stats);
        ranklist_kernel<<<NB, 256, 0, stream>>>(ei, E, cnt2, off, list);
        int groups = (E + 31) / 32;
        int mblocks = (groups < 2048) ? groups : 2048;   // 8 blocks/CU exactly
        edge_mlp_mfma_kernel<<<mblocks, 256, 0, stream>>>(
            xT, ei, ea, wmean, wstd, W1, b1, W2, b2, W3, acc, gbuf, N, E);
        node_sum_kernel<<<(N + 3) / 4, 256, 0, stream>>>(
            gbuf, off, list, b3, out, N);
    } else {
        hipMemsetAsync(d_out, 0, (size_t)out_size * sizeof(float), stream);
        prep_kernel<<<NB, 256, 0, stream>>>(ea, ei, x, xT, cnt2, acc, N, E, 0);
        finalize_stats_kernel<<<1, 1, 0, stream>>>(acc, E, stats);
        edge_atomic_kernel<<<eblocks, 256, 0, stream>>>(
            x, ei, ea, wmean, wstd, W1, b1, W2, b2, W3, stats, out, N, E);
        output_kernel<<<(out_size + 255) / 256, 256, 0, stream>>>(out, b3, out_size);
    }
}

// Round 16
// 108.649 us; speedup vs baseline: 1.1102x; 1.1102x over previous
//
#include <hip/hip_runtime.h>
#include <hip/hip_fp16.h>
#include <math.h>

#define BB 8        // batch count (fixed by problem instance)
#define NB 128      // counting-sort blocks (chunk owners) == ranklist-role blocks
#define NBINS 10016 // padded bin count; fast path requires N <= NBINS
#define FPAD 14     // fsh row stride in dwords (56B: 8B-aligned, bank-spread)

typedef float f32x2 __attribute__((ext_vector_type(2)));
typedef float f32x4 __attribute__((ext_vector_type(4)));
typedef _Float16 h16x4 __attribute__((ext_vector_type(4)));

__device__ __forceinline__ float sigmoidf_(float v) {
    return __builtin_amdgcn_rcpf(1.0f + __expf(-v));
}
__device__ __forceinline__ float sigs_(float d) {   // pre-activation scaled by log2(e)
    return __builtin_amdgcn_rcpf(1.0f + __builtin_amdgcn_exp2f(-d));
}
__device__ __forceinline__ unsigned pkh2_(float a, float b) {
    __half2 h = __floats2half2_rn(a, b);
    return *reinterpret_cast<unsigned*>(&h);
}

// ---- K1 prep: ea stats partials (deterministic, no zeroing needed) +
//      xT transpose + per-block LDS histogram -> cnt2 ----
__global__ __launch_bounds__(256) void prep_kernel(
    const float* __restrict__ ea, const int* __restrict__ ei,
    const float* __restrict__ x, float* __restrict__ xT,
    unsigned short* __restrict__ cnt2, double* __restrict__ accp,
    int N, int E, int full)
{
    __shared__ unsigned hist[NBINS];
    __shared__ double sh[4][256];
    int tid = threadIdx.x;
    int blk = blockIdx.x;

    if (full) {
        for (int b = tid; b < NBINS; b += 256) hist[b] = 0u;
    }

    double s0 = 0, q0 = 0, s1 = 0, q1 = 0;
    for (int i = blk * 256 + tid; i < E; i += NB * 256) {
        float a = ea[2 * i];
        float b = ea[2 * i + 1];
        s0 += (double)a; q0 += (double)a * (double)a;
        s1 += (double)b; q1 += (double)b * (double)b;
    }

    if (full) {
        int xtotal = N * BB * 3;
        for (int idx = blk * 256 + tid; idx < xtotal; idx += NB * 256) {
            int c = idx % 3;
            int rest = idx / 3;
            int n = rest % N;
            int b = rest / N;
            xT[n * 24 + b * 3 + c] = x[idx];
        }
        __syncthreads();
        int chunk = (E + NB - 1) / NB;
        int s = blk * chunk;
        int epd = min(E, s + chunk);
        for (int e = s + tid; e < epd; e += 256) {
            atomicAdd(&hist[ei[E + e]], 1u);   // tgt (+g)
            atomicAdd(&hist[ei[e]], 1u);       // src (-g)
        }
        __syncthreads();
        unsigned short* row = cnt2 + (size_t)blk * NBINS;
        for (int b = tid; b < NBINS; b += 256)
            row[b] = (unsigned short)hist[b];
    }

    sh[0][tid] = s0; sh[1][tid] = q0; sh[2][tid] = s1; sh[3][tid] = q1;
    __syncthreads();
    for (int off = 128; off > 0; off >>= 1) {
        if (tid < off) {
            sh[0][tid] += sh[0][tid + off];
            sh[1][tid] += sh[1][tid + off];
            sh[2][tid] += sh[2][tid + off];
            sh[3][tid] += sh[3][tid + off];
        }
        __syncthreads();
    }
    if (tid == 0) {
        accp[4 * blk + 0] = sh[0][0];
        accp[4 * blk + 1] = sh[1][0];
        accp[4 * blk + 2] = sh[2][0];
        accp[4 * blk + 3] = sh[3][0];
    }
}

// ---- K2 base: per-bin exclusive prefix over blocks (in-place) + totals ----
__global__ __launch_bounds__(256) void base_kernel(unsigned short* __restrict__ cnt2,
                                                   int* __restrict__ tot) {
    int bin = blockIdx.x * 256 + threadIdx.x;
    if (bin >= NBINS) return;
    unsigned run = 0;
    #pragma unroll 8
    for (int blk = 0; blk < NB; blk++) {
        size_t idx = (size_t)blk * NBINS + bin;
        unsigned v = cnt2[idx];
        cnt2[idx] = (unsigned short)run;
        run += v;
    }
    tot[bin] = (int)run;
}

// ---- K3 scan: exclusive scan over node totals + stats finalize from partials ----
__global__ __launch_bounds__(1024) void scan_kernel(const int* __restrict__ tot,
                                                    int* __restrict__ off, int N,
                                                    const double* __restrict__ accp, int E,
                                                    float* __restrict__ stats) {
    if (threadIdx.x == 0) {
        double s0 = 0, q0 = 0, s1 = 0, q1 = 0;
        for (int b = 0; b < NB; b++) {
            s0 += accp[4 * b + 0];
            q0 += accp[4 * b + 1];
            s1 += accp[4 * b + 2];
            q1 += accp[4 * b + 3];
        }
        double v0 = (q0 - s0 * s0 / E) / (double)(E - 1);
        double v1 = (q1 - s1 * s1 / E) / (double)(E - 1);
        stats[0] = (float)(s0 / E);
        stats[1] = (float)(1.0 / sqrt(v0));
        stats[2] = (float)(s1 / E);
        stats[3] = (float)(1.0 / sqrt(v1));
    }
    __shared__ int sh[1024];
    int t = threadIdx.x;
    int chunk = (N + 1023) >> 10;
    int lo = t * chunk;
    int hi = lo + chunk; if (hi > N) hi = N;
    int s = 0;
    for (int i = lo; i < hi; i++) s += tot[i];
    sh[t] = s;
    __syncthreads();
    for (int d = 1; d < 1024; d <<= 1) {
        int v = (t >= d) ? sh[t - d] : 0;
        __syncthreads();
        sh[t] += v;
        __syncthreads();
    }
    int run = (t == 0) ? 0 : sh[t - 1];
    for (int i = lo; i < hi; i++) {
        off[i] = run;
        run += tot[i];
    }
    if (t == 1023) off[N] = sh[1023];
}

// ---- K4 (fused, role-split): ranklist (blocks 0..NB-1) ∥ MFMA MLP (rest) ----
// Shared-memory union: ranklist uses smem as hist[NBINS] (40KB); MLP blocks
// reuse the same allocation as fsh[4][64][FPAD] (14KB). 40KB -> 4 blocks/CU.
// ranklist (~13us) hides completely under the MLP (~45us).
// NB: every LDS dword B1 reads (fp[0..7]) MUST be initialized — 0 x NaN = NaN.
__global__ __launch_bounds__(256) void fused_rank_mlp_kernel(
    const float* __restrict__ xT, const int* __restrict__ ei,
    const float* __restrict__ ea,
    const float* __restrict__ wmean, const float* __restrict__ wstd,
    const float* __restrict__ W1, const float* __restrict__ b1,
    const float* __restrict__ W2, const float* __restrict__ b2,
    const float* __restrict__ W3,
    const float* __restrict__ stats,
    const unsigned short* __restrict__ cnt2,
    const int* __restrict__ off, int* __restrict__ list,
    uint2* __restrict__ gbuf,
    int N, int E)
{
    __shared__ unsigned smem[NBINS];   // union: hist (rank role) / fsh (mlp role)
    int tid = threadIdx.x;

    if (blockIdx.x < NB) {
        // ---------------- ranklist role ----------------
        unsigned* hist = smem;
        int blk = blockIdx.x;
        for (int b = tid; b < NBINS; b += 256) hist[b] = 0u;
        __syncthreads();
        int chunk = (E + NB - 1) / NB;
        int s = blk * chunk;
        int epd = min(E, s + chunk);
        const unsigned short* row = cnt2 + (size_t)blk * NBINS;
        for (int e = s + tid; e < epd; e += 256) {
            int tgt = ei[E + e];
            int src = ei[e];
            unsigned lt = atomicAdd(&hist[tgt], 1u);
            unsigned ls = atomicAdd(&hist[src], 1u);
            list[off[tgt] + (int)row[tgt] + (int)lt] = e;
            list[off[src] + (int)row[src] + (int)ls] = e | 0x80000000;
        }
        return;
    }

    // ---------------- MFMA MLP role ----------------
    typedef unsigned fsh_t[64][FPAD];
    fsh_t* fsh = reinterpret_cast<fsh_t*>(smem);   // [wave][pair][FPAD dwords]

    int mlp_id = blockIdx.x - NB;
    int nmlp = gridDim.x - NB;
    int lane = tid & 63;
    int wave = tid >> 6;
    int g = lane >> 4;        // k-group / row-group
    int arow = lane & 15;     // A row / D col

    const float LOG2E = 1.44269504088896340736f;

    float st0 = stats[0], st1 = stats[1], st2 = stats[2], st3 = stats[3];

    // preload weight fragments (constant across steps)
    h16x4 A1, A2a, A2b, A3a, A3b;
    #pragma unroll
    for (int j = 0; j < 4; j++) {
        int k = 4 * g + j;
        A1[j]  = (_Float16)((k < 9) ? W1[k * 16 + arow] * LOG2E : 0.0f);
        A2a[j] = (_Float16)(W2[k * 30 + arow] * LOG2E);
        A2b[j] = (_Float16)((arow < 14) ? W2[k * 30 + 16 + arow] * LOG2E : 0.0f);
        A3a[j] = (_Float16)((arow < 3) ? W3[k * 3 + arow] : 0.0f);
        int k2 = 16 + k;
        A3b[j] = (_Float16)((arow < 3 && k2 < 30) ? W3[k2 * 3 + arow] : 0.0f);
    }
    f32x4 C1, C2a, C2b;
    #pragma unroll
    for (int r = 0; r < 4; r++) {
        int row = 4 * g + r;
        C1[r]  = b1[row] * LOG2E;
        C2a[r] = b2[row] * LOG2E;
        C2b[r] = (row < 14) ? b2[16 + row] * LOG2E : 0.0f;
    }

    float wm0 = wmean[0], wm1 = wmean[1];
    float wsd0 = wstd[0], wsd1 = wstd[1];

    int e_loc = lane >> 3;    // 0..7 : edge within step
    int bb = lane & 7;        // 0..7 : batch

    for (int grp = mlp_id; grp * 32 < E; grp += nmlp) {
        int ebase = grp * 32 + wave * 8;
        if (ebase >= E) continue;

        int e = ebase + e_loc;
        int esafe = (e < E) ? e : (E - 1);
        int src = ei[esafe];
        int tgt = ei[E + esafe];
        float dist = ea[2 * esafe];
        float cdir = ea[2 * esafe + 1];

        const float* xs = xT + src * 24 + bb * 3;
        const float* xt = xT + tgt * 24 + bb * 3;
        float s0 = xs[0], s1 = xs[1], s2 = xs[2];
        float t0 = xt[0], t1 = xt[1], t2 = xt[2];
        float ea0 = (dist - st0) * st1;
        float ea1 = (cdir - st2) * st3;
        float speed = fmaf(s1, wsd0, wm0);
        float direc = fmaf(s2, wsd1, wm1);
        float theta = fabsf(cdir - direc);
        float ew = fmaxf(0.0f, speed * __cosf(theta) * 3.0f * __builtin_amdgcn_rcpf(dist));

        // pack 9 feats to f16, stash in LDS; zero-fill through fp[7]
        unsigned* fp = &fsh[wave][lane][0];
        uint4 wv0, wv1;
        wv0.x = pkh2_(s0, s1); wv0.y = pkh2_(s2, t0);
        wv0.z = pkh2_(t1, t2); wv0.w = pkh2_(ea0, ea1);
        wv1.x = pkh2_(ew, 0.0f); wv1.y = 0u; wv1.z = 0u; wv1.w = 0u;
        *reinterpret_cast<uint4*>(fp) = wv0;
        *reinterpret_cast<uint4*>(fp + 4) = wv1;

        // MFMA phase: 4 tiles of 16 cols
        #pragma unroll
        for (int t = 0; t < 4; t++) {
            const unsigned* q = &fsh[wave][t * 16 + arow][0];
            union { uint2 u; h16x4 h; } b1u;
            b1u.u = *reinterpret_cast<const uint2*>(q + 2 * g);

            f32x4 D1 = __builtin_amdgcn_mfma_f32_16x16x16f16(A1, b1u.h, C1, 0, 0, 0);
            union { uint2 u; h16x4 h; } b2u;
            b2u.u.x = pkh2_(sigs_(D1[0]), sigs_(D1[1]));
            b2u.u.y = pkh2_(sigs_(D1[2]), sigs_(D1[3]));

            f32x4 D2a = __builtin_amdgcn_mfma_f32_16x16x16f16(A2a, b2u.h, C2a, 0, 0, 0);
            f32x4 D2b = __builtin_amdgcn_mfma_f32_16x16x16f16(A2b, b2u.h, C2b, 0, 0, 0);
            union { uint2 u; h16x4 h; } b3au, b3bu;
            b3au.u.x = pkh2_(sigs_(D2a[0]), sigs_(D2a[1]));
            b3au.u.y = pkh2_(sigs_(D2a[2]), sigs_(D2a[3]));
            b3bu.u.x = pkh2_(sigs_(D2b[0]), sigs_(D2b[1]));
            b3bu.u.y = pkh2_(sigs_(D2b[2]), sigs_(D2b[3]));

            f32x4 Z = {0.f, 0.f, 0.f, 0.f};
            f32x4 D3 = __builtin_amdgcn_mfma_f32_16x16x16f16(A3a, b3au.h, Z, 0, 0, 0);
            D3 = __builtin_amdgcn_mfma_f32_16x16x16f16(A3b, b3bu.h, D3, 0, 0, 0);

            if (g == 0) {
                int et = ebase + 2 * t + (arow >> 3);   // edge of this col
                int bt = arow & 7;                      // batch of this col
                if (et < E) {
                    uint2 wp;
                    wp.x = pkh2_(D3[0], D3[1]);
                    wp.y = pkh2_(D3[2], 0.0f);
                    gbuf[(size_t)et * BB + bt] = wp;    // 16 lanes -> 128B linear
                }
            }
        }
    }
}

// ---- K5: one wave per node; each lane consumes one full 64B edge-line ----
__global__ __launch_bounds__(256) void node_sum_kernel(
    const uint2* __restrict__ gbuf, const int* __restrict__ off,
    const int* __restrict__ list,
    const float* __restrict__ b3, float* __restrict__ out, int N)
{
    int node = blockIdx.x * 4 + (threadIdx.x >> 6);
    int lane = threadIdx.x & 63;
    if (node >= N) return;

    int o0 = off[node], o1 = off[node + 1];
    float a[BB][3];
    #pragma unroll
    for (int b = 0; b < BB; b++) { a[b][0] = 0.f; a[b][1] = 0.f; a[b][2] = 0.f; }

    for (int i = o0 + lane; i < o1; i += 64) {
        int entry = list[i];
        int e = entry & 0x7FFFFFFF;
        float sgn = (entry < 0) ? -1.0f : 1.0f;
        const uint4* gl = reinterpret_cast<const uint4*>(gbuf + (size_t)e * BB);
        uint4 q0 = gl[0], q1 = gl[1], q2 = gl[2], q3 = gl[3];

        #define ACC_(bi, u01, u2x) {                                              \
            float2 f01 = __half22float2(*reinterpret_cast<const __half2*>(&u01)); \
            float2 f2  = __half22float2(*reinterpret_cast<const __half2*>(&u2x)); \
            a[bi][0] = fmaf(sgn, f01.x, a[bi][0]);                                \
            a[bi][1] = fmaf(sgn, f01.y, a[bi][1]);                                \
            a[bi][2] = fmaf(sgn, f2.x,  a[bi][2]); }
        ACC_(0, q0.x, q0.y) ACC_(1, q0.z, q0.w)
        ACC_(2, q1.x, q1.y) ACC_(3, q1.z, q1.w)
        ACC_(4, q2.x, q2.y) ACC_(5, q2.z, q2.w)
        ACC_(6, q3.x, q3.y) ACC_(7, q3.z, q3.w)
        #undef ACC_
    }

    #pragma unroll
    for (int m = 32; m >= 1; m >>= 1) {
        #pragma unroll
        for (int b = 0; b < BB; b++) {
            a[b][0] += __shfl_xor(a[b][0], m);
            a[b][1] += __shfl_xor(a[b][1], m);
            a[b][2] += __shfl_xor(a[b][2], m);
        }
    }

    float bb0 = b3[0], bb1 = b3[1], bb2 = b3[2];
    #pragma unroll
    for (int b = 0; b < BB; b++) {
        if (lane == b) {
            float* o = out + ((size_t)b * N + node) * 3;
            o[0] = sigmoidf_(a[b][0] + bb0);
            o[1] = sigmoidf_(a[b][1] + bb1);
            o[2] = sigmoidf_(a[b][2] + bb2);
        }
    }
}

// ---- Fallback path (small ws or N > NBINS): scalar MLP + atomic scatter ----
__global__ void finalize_stats_kernel(const double* __restrict__ accp, int E,
                                      float* __restrict__ stats) {
    double s0 = 0, q0 = 0, s1 = 0, q1 = 0;
    for (int b = 0; b < NB; b++) {
        s0 += accp[4 * b + 0];
        q0 += accp[4 * b + 1];
        s1 += accp[4 * b + 2];
        q1 += accp[4 * b + 3];
    }
    double v0 = (q0 - s0 * s0 / E) / (double)(E - 1);
    double v1 = (q1 - s1 * s1 / E) / (double)(E - 1);
    stats[0] = (float)(s0 / E);
    stats[1] = (float)(1.0 / sqrt(v0));
    stats[2] = (float)(s1 / E);
    stats[3] = (float)(1.0 / sqrt(v1));
}

__device__ __forceinline__ void mlp_eval(
    const float feat[9],
    const float* __restrict__ W1, const float* __restrict__ b1,
    const float* __restrict__ W2, const float* __restrict__ b2,
    const float* __restrict__ W3,
    float& g0, float& g1, float& g2)
{
    const f32x2* W1p = (const f32x2*)W1;
    const f32x2* b1p = (const f32x2*)b1;
    f32x2 acc1[8];
    #pragma unroll
    for (int j = 0; j < 8; j++) acc1[j] = b1p[j];
    #pragma unroll
    for (int k = 0; k < 9; k++) {
        f32x2 fk2 = {feat[k], feat[k]};
        #pragma unroll
        for (int j = 0; j < 8; j++)
            acc1[j] = __builtin_elementwise_fma(fk2, W1p[k * 8 + j], acc1[j]);
    }
    float h1[16];
    #pragma unroll
    for (int j = 0; j < 8; j++) {
        h1[2 * j]     = sigmoidf_(acc1[j].x);
        h1[2 * j + 1] = sigmoidf_(acc1[j].y);
    }
    const f32x2* W2p = (const f32x2*)W2;
    const f32x2* b2p = (const f32x2*)b2;
    f32x2 acc2[15];
    #pragma unroll
    for (int k = 0; k < 15; k++) acc2[k] = b2p[k];
    #pragma unroll
    for (int j = 0; j < 16; j++) {
        f32x2 hj2 = {h1[j], h1[j]};
        #pragma unroll
        for (int k = 0; k < 15; k++)
            acc2[k] = __builtin_elementwise_fma(hj2, W2p[j * 15 + k], acc2[k]);
    }
    g0 = 0.f; g1 = 0.f; g2 = 0.f;
    #pragma unroll
    for (int k = 0; k < 15; k++) {
        float ha = sigmoidf_(acc2[k].x);
        float hb = sigmoidf_(acc2[k].y);
        int ka = 2 * k, kb = 2 * k + 1;
        g0 = fmaf(ha, W3[ka * 3 + 0], g0); g0 = fmaf(hb, W3[kb * 3 + 0], g0);
        g1 = fmaf(ha, W3[ka * 3 + 1], g1); g1 = fmaf(hb, W3[kb * 3 + 1], g1);
        g2 = fmaf(ha, W3[ka * 3 + 2], g2); g2 = fmaf(hb, W3[kb * 3 + 2], g2);
    }
}

__global__ __launch_bounds__(256) void edge_atomic_kernel(
    const float* __restrict__ x, const int* __restrict__ ei,
    const float* __restrict__ ea,
    const float* __restrict__ wmean, const float* __restrict__ wstd,
    const float* __restrict__ W1, const float* __restrict__ b1,
    const float* __restrict__ W2, const float* __restrict__ b2,
    const float* __restrict__ W3,
    const float* __restrict__ stats,
    float* __restrict__ out, int N, int E)
{
    int e = blockIdx.x * blockDim.x + threadIdx.x;
    if (e >= E) return;
    int src = ei[e];
    int tgt = ei[E + e];
    float dist = ea[2 * e];
    float cdir = ea[2 * e + 1];
    float ea0 = (dist - stats[0]) * stats[1];
    float ea1 = (cdir - stats[2]) * stats[3];

    for (int b = 0; b < BB; b++) {
        const float* xb = x + (size_t)b * N * 3;
        float s0 = xb[src * 3 + 0], s1 = xb[src * 3 + 1], s2 = xb[src * 3 + 2];
        float t0 = xb[tgt * 3 + 0], t1 = xb[tgt * 3 + 1], t2 = xb[tgt * 3 + 2];
        float speed = fmaf(s1, wstd[0], wmean[0]);
        float direc = fmaf(s2, wstd[1], wmean[1]);
        float theta = fabsf(cdir - direc);
        float ew = fmaxf(0.0f, speed * __cosf(theta) * 3.0f * __builtin_amdgcn_rcpf(dist));
        float feat[9] = {s0, s1, s2, t0, t1, t2, ea0, ea1, ew};
        float g0, g1, g2;
        mlp_eval(feat, W1, b1, W2, b2, W3, g0, g1, g2);
        float* ot = out + ((size_t)b * N + tgt) * 3;
        float* os = out + ((size_t)b * N + src) * 3;
        atomicAdd(&ot[0], g0);  atomicAdd(&ot[1], g1);  atomicAdd(&ot[2], g2);
        atomicAdd(&os[0], -g0); atomicAdd(&os[1], -g1); atomicAdd(&os[2], -g2);
    }
}

__global__ void output_kernel(float* __restrict__ out, const float* __restrict__ b3, int total) {
    int i = blockIdx.x * blockDim.x + threadIdx.x;
    if (i < total) out[i] = sigmoidf_(out[i] + b3[i % 3]);
}

extern "C" void kernel_launch(void* const* d_in, const int* in_sizes, int n_in,
                              void* d_out, int out_size, void* d_ws, size_t ws_size,
                              hipStream_t stream) {
    const float* x     = (const float*)d_in[0];
    const int*   ei    = (const int*)d_in[1];
    const float* ea    = (const float*)d_in[2];
    const float* wmean = (const float*)d_in[3];
    const float* wstd  = (const float*)d_in[4];
    const float* W1    = (const float*)d_in[5];
    const float* b1    = (const float*)d_in[6];
    const float* W2    = (const float*)d_in[7];
    const float* b2    = (const float*)d_in[8];
    const float* W3    = (const float*)d_in[9];
    const float* b3    = (const float*)d_in[10];

    int E = in_sizes[2] / 2;        // edge_attr is (E, 2)
    int N = in_sizes[0] / (BB * 3); // x is (B, N, 3)

    float* out = (float*)d_out;
    char* ws = (char*)d_ws;

    // layout: [accp NB*4 dbl][stats 4 f][tot NBINS][off N+1][list 2E][xT N*24 f][cnt2 NB*NBINS u16][gbuf E*8 uint2]
    double* accp  = (double*)ws;                       // NB*4 doubles = 4KB
    float*  stats = (float*)(ws + NB * 4 * sizeof(double));       // 16 B (+pad)
    int*    tot   = (int*)(ws + NB * 4 * sizeof(double) + 64);    // NBINS
    int*    off   = tot + NBINS;                       // N+1
    int*    list  = off + N + 1;                       // 2E

    size_t xtOff = NB * 4 * sizeof(double) + 64 +
                   sizeof(int) * ((size_t)NBINS + (N + 1) + 2 * (size_t)E);
    xtOff = (xtOff + 255) & ~(size_t)255;
    float* xT = (float*)(ws + xtOff);

    size_t c2Off = xtOff + (size_t)N * 24 * sizeof(float);
    c2Off = (c2Off + 255) & ~(size_t)255;
    unsigned short* cnt2 = (unsigned short*)(ws + c2Off);

    size_t gbOff = c2Off + (size_t)NB * NBINS * sizeof(unsigned short);
    gbOff = (gbOff + 255) & ~(size_t)255;
    uint2* gbuf = (uint2*)(ws + gbOff);
    size_t needed = gbOff + (size_t)E * BB * sizeof(uint2);

    int eblocks = (E + 255) / 256;
    int fastPath = (needed <= ws_size && N <= NBINS) ? 1 : 0;

    if (fastPath) {
        prep_kernel<<<NB, 256, 0, stream>>>(ea, ei, x, xT, cnt2, accp, N, E, 1);
        base_kernel<<<(NBINS + 255) / 256, 256, 0, stream>>>(cnt2, tot);
        scan_kernel<<<1, 1024, 0, stream>>>(tot, off, N, accp, E, stats);
        fused_rank_mlp_kernel<<<NB + 1920, 256, 0, stream>>>(
            xT, ei, ea, wmean, wstd, W1, b1, W2, b2, W3, stats,
            cnt2, off, list, gbuf, N, E);
        node_sum_kernel<<<(N + 3) / 4, 256, 0, stream>>>(
            gbuf, off, list, b3, out, N);
    } else {
        hipMemsetAsync(d_out, 0, (size_t)out_size * sizeof(float), stream);
        prep_kernel<<<NB, 256, 0, stream>>>(ea, ei, x, xT, cnt2, accp, N, E, 0);
        finalize_stats_kernel<<<1, 1, 0, stream>>>(accp, E, stats);
        edge_atomic_kernel<<<eblocks, 256, 0, stream>>>(
            x, ei, ea, wmean, wstd, W1, b1, W2, b2, W3, stats, out, N, E);
        output_kernel<<<(out_size + 255) / 256, 256, 0, stream>>>(out, b3, out_size);
    }
}

// Round 17
// 105.390 us; speedup vs baseline: 1.1446x; 1.0309x over previous
//
#include <hip/hip_runtime.h>
#include <hip/hip_fp16.h>
#include <math.h>

#define BB 8        // batch count (fixed by problem instance)
#define NB 128      // counting-sort blocks (chunk owners) == ranklist-role blocks
#define NBINS 10016 // padded bin count; fast path requires N <= NBINS
#define NBINSW 5008 // packed histogram words (2 u16 bins per u32)
#define FPAD 14     // fsh row stride in dwords (56B: 8B-aligned, bank-spread)

typedef float f32x2 __attribute__((ext_vector_type(2)));
typedef float f32x4 __attribute__((ext_vector_type(4)));
typedef _Float16 h16x4 __attribute__((ext_vector_type(4)));

__device__ __forceinline__ float sigmoidf_(float v) {
    return __builtin_amdgcn_rcpf(1.0f + __expf(-v));
}
__device__ __forceinline__ float sigs_(float d) {   // pre-activation scaled by log2(e)
    return __builtin_amdgcn_rcpf(1.0f + __builtin_amdgcn_exp2f(-d));
}
__device__ __forceinline__ unsigned pkh2_(float a, float b) {
    __half2 h = __floats2half2_rn(a, b);
    return *reinterpret_cast<unsigned*>(&h);
}
// packed u16-bin histogram helpers: bin b lives in half (b&1) of word (b>>1).
// Max count per block-chunk is 5008 < 65536, so low-half adds never carry.
__device__ __forceinline__ unsigned hinc_(unsigned* hh, int b) {
    unsigned sh = (b & 1) * 16;
    unsigned old = atomicAdd(&hh[b >> 1], 1u << sh);
    return (old >> sh) & 0xFFFFu;
}

// ---- K1 prep: ea stats partials + xT transpose + packed LDS histogram -> cnt2 ----
__global__ __launch_bounds__(256) void prep_kernel(
    const float* __restrict__ ea, const int* __restrict__ ei,
    const float* __restrict__ x, float* __restrict__ xT,
    unsigned short* __restrict__ cnt2, double* __restrict__ accp,
    int N, int E, int full)
{
    __shared__ unsigned hh[NBINSW];
    __shared__ double sh[4][256];
    int tid = threadIdx.x;
    int blk = blockIdx.x;

    if (full) {
        for (int b = tid; b < NBINSW; b += 256) hh[b] = 0u;
    }

    double s0 = 0, q0 = 0, s1 = 0, q1 = 0;
    for (int i = blk * 256 + tid; i < E; i += NB * 256) {
        float a = ea[2 * i];
        float b = ea[2 * i + 1];
        s0 += (double)a; q0 += (double)a * (double)a;
        s1 += (double)b; q1 += (double)b * (double)b;
    }

    if (full) {
        int xtotal = N * BB * 3;
        for (int idx = blk * 256 + tid; idx < xtotal; idx += NB * 256) {
            int c = idx % 3;
            int rest = idx / 3;
            int n = rest % N;
            int b = rest / N;
            xT[n * 24 + b * 3 + c] = x[idx];
        }
        __syncthreads();
        int chunk = (E + NB - 1) / NB;
        int s = blk * chunk;
        int epd = min(E, s + chunk);
        for (int e = s + tid; e < epd; e += 256) {
            hinc_(hh, ei[E + e]);   // tgt (+g)
            hinc_(hh, ei[e]);       // src (-g)
        }
        __syncthreads();
        unsigned short* row = cnt2 + (size_t)blk * NBINS;
        for (int b = tid; b < NBINS; b += 256)
            row[b] = (unsigned short)((hh[b >> 1] >> ((b & 1) * 16)) & 0xFFFFu);
    }

    sh[0][tid] = s0; sh[1][tid] = q0; sh[2][tid] = s1; sh[3][tid] = q1;
    __syncthreads();
    for (int off = 128; off > 0; off >>= 1) {
        if (tid < off) {
            sh[0][tid] += sh[0][tid + off];
            sh[1][tid] += sh[1][tid + off];
            sh[2][tid] += sh[2][tid + off];
            sh[3][tid] += sh[3][tid + off];
        }
        __syncthreads();
    }
    if (tid == 0) {
        accp[4 * blk + 0] = sh[0][0];
        accp[4 * blk + 1] = sh[1][0];
        accp[4 * blk + 2] = sh[2][0];
        accp[4 * blk + 3] = sh[3][0];
    }
}

// ---- K2 base: per-bin exclusive prefix over blocks (in-place) + totals ----
__global__ __launch_bounds__(256) void base_kernel(unsigned short* __restrict__ cnt2,
                                                   int* __restrict__ tot) {
    int bin = blockIdx.x * 256 + threadIdx.x;
    if (bin >= NBINS) return;
    unsigned run = 0;
    #pragma unroll 8
    for (int blk = 0; blk < NB; blk++) {
        size_t idx = (size_t)blk * NBINS + bin;
        unsigned v = cnt2[idx];
        cnt2[idx] = (unsigned short)run;
        run += v;
    }
    tot[bin] = (int)run;
}

// ---- K3 scan: exclusive scan over node totals + stats finalize from partials ----
__global__ __launch_bounds__(1024) void scan_kernel(const int* __restrict__ tot,
                                                    int* __restrict__ off, int N,
                                                    const double* __restrict__ accp, int E,
                                                    float* __restrict__ stats) {
    if (threadIdx.x == 0) {
        double s0 = 0, q0 = 0, s1 = 0, q1 = 0;
        for (int b = 0; b < NB; b++) {
            s0 += accp[4 * b + 0];
            q0 += accp[4 * b + 1];
            s1 += accp[4 * b + 2];
            q1 += accp[4 * b + 3];
        }
        double v0 = (q0 - s0 * s0 / E) / (double)(E - 1);
        double v1 = (q1 - s1 * s1 / E) / (double)(E - 1);
        stats[0] = (float)(s0 / E);
        stats[1] = (float)(1.0 / sqrt(v0));
        stats[2] = (float)(s1 / E);
        stats[3] = (float)(1.0 / sqrt(v1));
    }
    __shared__ int sh[1024];
    int t = threadIdx.x;
    int chunk = (N + 1023) >> 10;
    int lo = t * chunk;
    int hi = lo + chunk; if (hi > N) hi = N;
    int s = 0;
    for (int i = lo; i < hi; i++) s += tot[i];
    sh[t] = s;
    __syncthreads();
    for (int d = 1; d < 1024; d <<= 1) {
        int v = (t >= d) ? sh[t - d] : 0;
        __syncthreads();
        sh[t] += v;
        __syncthreads();
    }
    int run = (t == 0) ? 0 : sh[t - 1];
    for (int i = lo; i < hi; i++) {
        off[i] = run;
        run += tot[i];
    }
    if (t == 1023) off[N] = sh[1023];
}

// ---- K4 (fused, role-split): ranklist (blocks 0..NB-1) ∥ MFMA MLP (rest) ----
// Shared-memory union: ranklist uses packed hist (20KB); MLP reuses it as
// fsh[4][64][FPAD] (14KB). 20KB -> 8 blocks/CU (full wave budget).
// NB: every LDS dword B1 reads (fp[0..7]) MUST be initialized — 0 x NaN = NaN.
__global__ __launch_bounds__(256) void fused_rank_mlp_kernel(
    const float* __restrict__ xT, const int* __restrict__ ei,
    const float* __restrict__ ea,
    const float* __restrict__ wmean, const float* __restrict__ wstd,
    const float* __restrict__ W1, const float* __restrict__ b1,
    const float* __restrict__ W2, const float* __restrict__ b2,
    const float* __restrict__ W3,
    const float* __restrict__ stats,
    const unsigned short* __restrict__ cnt2,
    const int* __restrict__ off, int* __restrict__ list,
    uint2* __restrict__ gbuf,
    int N, int E)
{
    __shared__ unsigned smem[NBINSW];   // union: packed hist / fsh
    int tid = threadIdx.x;

    if (blockIdx.x < NB) {
        // ---------------- ranklist role ----------------
        unsigned* hh = smem;
        int blk = blockIdx.x;
        for (int b = tid; b < NBINSW; b += 256) hh[b] = 0u;
        __syncthreads();
        int chunk = (E + NB - 1) / NB;
        int s = blk * chunk;
        int epd = min(E, s + chunk);
        const unsigned short* row = cnt2 + (size_t)blk * NBINS;
        for (int e = s + tid; e < epd; e += 256) {
            int tgt = ei[E + e];
            int src = ei[e];
            unsigned lt = hinc_(hh, tgt);
            unsigned ls = hinc_(hh, src);
            list[off[tgt] + (int)row[tgt] + (int)lt] = e;
            list[off[src] + (int)row[src] + (int)ls] = e | 0x80000000;
        }
        return;
    }

    // ---------------- MFMA MLP role ----------------
    typedef unsigned fsh_t[64][FPAD];
    fsh_t* fsh = reinterpret_cast<fsh_t*>(smem);   // [wave][pair][FPAD dwords]

    int mlp_id = blockIdx.x - NB;
    int nmlp = gridDim.x - NB;
    int lane = tid & 63;
    int wave = tid >> 6;
    int g = lane >> 4;        // k-group / row-group
    int arow = lane & 15;     // A row / D col

    const float LOG2E = 1.44269504088896340736f;

    float st0 = stats[0], st1 = stats[1], st2 = stats[2], st3 = stats[3];

    // preload weight fragments (constant across steps)
    h16x4 A1, A2a, A2b, A3a, A3b;
    #pragma unroll
    for (int j = 0; j < 4; j++) {
        int k = 4 * g + j;
        A1[j]  = (_Float16)((k < 9) ? W1[k * 16 + arow] * LOG2E : 0.0f);
        A2a[j] = (_Float16)(W2[k * 30 + arow] * LOG2E);
        A2b[j] = (_Float16)((arow < 14) ? W2[k * 30 + 16 + arow] * LOG2E : 0.0f);
        A3a[j] = (_Float16)((arow < 3) ? W3[k * 3 + arow] : 0.0f);
        int k2 = 16 + k;
        A3b[j] = (_Float16)((arow < 3 && k2 < 30) ? W3[k2 * 3 + arow] : 0.0f);
    }
    f32x4 C1, C2a, C2b;
    #pragma unroll
    for (int r = 0; r < 4; r++) {
        int row = 4 * g + r;
        C1[r]  = b1[row] * LOG2E;
        C2a[r] = b2[row] * LOG2E;
        C2b[r] = (row < 14) ? b2[16 + row] * LOG2E : 0.0f;
    }

    float wm0 = wmean[0], wm1 = wmean[1];
    float wsd0 = wstd[0], wsd1 = wstd[1];

    int e_loc = lane >> 3;    // 0..7 : edge within step
    int bb = lane & 7;        // 0..7 : batch

    for (int grp = mlp_id; grp * 32 < E; grp += nmlp) {
        int ebase = grp * 32 + wave * 8;
        if (ebase >= E) continue;

        int e = ebase + e_loc;
        int esafe = (e < E) ? e : (E - 1);
        int src = ei[esafe];
        int tgt = ei[E + esafe];
        float dist = ea[2 * esafe];
        float cdir = ea[2 * esafe + 1];

        const float* xs = xT + src * 24 + bb * 3;
        const float* xt = xT + tgt * 24 + bb * 3;
        float s0 = xs[0], s1 = xs[1], s2 = xs[2];
        float t0 = xt[0], t1 = xt[1], t2 = xt[2];
        float ea0 = (dist - st0) * st1;
        float ea1 = (cdir - st2) * st3;
        float speed = fmaf(s1, wsd0, wm0);
        float direc = fmaf(s2, wsd1, wm1);
        float theta = fabsf(cdir - direc);
        float ew = fmaxf(0.0f, speed * __cosf(theta) * 3.0f * __builtin_amdgcn_rcpf(dist));

        // pack 9 feats to f16, stash in LDS; zero-fill through fp[7]
        unsigned* fp = &fsh[wave][lane][0];
        uint4 wv0, wv1;
        wv0.x = pkh2_(s0, s1); wv0.y = pkh2_(s2, t0);
        wv0.z = pkh2_(t1, t2); wv0.w = pkh2_(ea0, ea1);
        wv1.x = pkh2_(ew, 0.0f); wv1.y = 0u; wv1.z = 0u; wv1.w = 0u;
        *reinterpret_cast<uint4*>(fp) = wv0;
        *reinterpret_cast<uint4*>(fp + 4) = wv1;

        // MFMA phase: 4 tiles of 16 cols
        #pragma unroll
        for (int t = 0; t < 4; t++) {
            const unsigned* q = &fsh[wave][t * 16 + arow][0];
            union { uint2 u; h16x4 h; } b1u;
            b1u.u = *reinterpret_cast<const uint2*>(q + 2 * g);

            f32x4 D1 = __builtin_amdgcn_mfma_f32_16x16x16f16(A1, b1u.h, C1, 0, 0, 0);
            union { uint2 u; h16x4 h; } b2u;
            b2u.u.x = pkh2_(sigs_(D1[0]), sigs_(D1[1]));
            b2u.u.y = pkh2_(sigs_(D1[2]), sigs_(D1[3]));

            f32x4 D2a = __builtin_amdgcn_mfma_f32_16x16x16f16(A2a, b2u.h, C2a, 0, 0, 0);
            f32x4 D2b = __builtin_amdgcn_mfma_f32_16x16x16f16(A2b, b2u.h, C2b, 0, 0, 0);
            union { uint2 u; h16x4 h; } b3au, b3bu;
            b3au.u.x = pkh2_(sigs_(D2a[0]), sigs_(D2a[1]));
            b3au.u.y = pkh2_(sigs_(D2a[2]), sigs_(D2a[3]));
            b3bu.u.x = pkh2_(sigs_(D2b[0]), sigs_(D2b[1]));
            b3bu.u.y = pkh2_(sigs_(D2b[2]), sigs_(D2b[3]));

            f32x4 Z = {0.f, 0.f, 0.f, 0.f};
            f32x4 D3 = __builtin_amdgcn_mfma_f32_16x16x16f16(A3a, b3au.h, Z, 0, 0, 0);
            D3 = __builtin_amdgcn_mfma_f32_16x16x16f16(A3b, b3bu.h, D3, 0, 0, 0);

            if (g == 0) {
                int et = ebase + 2 * t + (arow >> 3);   // edge of this col
                int bt = arow & 7;                      // batch of this col
                if (et < E) {
                    uint2 wp;
                    wp.x = pkh2_(D3[0], D3[1]);
                    wp.y = pkh2_(D3[2], 0.0f);
                    gbuf[(size_t)et * BB + bt] = wp;    // 16 lanes -> 128B linear
                }
            }
        }
    }
}

// ---- K5: one wave per node; each lane consumes one full 64B edge-line ----
__global__ __launch_bounds__(256) void node_sum_kernel(
    const uint2* __restrict__ gbuf, const int* __restrict__ off,
    const int* __restrict__ list,
    const float* __restrict__ b3, float* __restrict__ out, int N)
{
    int node = blockIdx.x * 4 + (threadIdx.x >> 6);
    int lane = threadIdx.x & 63;
    if (node >= N) return;

    int o0 = off[node], o1 = off[node + 1];
    float a[BB][3];
    #pragma unroll
    for (int b = 0; b < BB; b++) { a[b][0] = 0.f; a[b][1] = 0.f; a[b][2] = 0.f; }

    for (int i = o0 + lane; i < o1; i += 64) {
        int entry = list[i];
        int e = entry & 0x7FFFFFFF;
        float sgn = (entry < 0) ? -1.0f : 1.0f;
        const uint4* gl = reinterpret_cast<const uint4*>(gbuf + (size_t)e * BB);
        uint4 q0 = gl[0], q1 = gl[1], q2 = gl[2], q3 = gl[3];

        #define ACC_(bi, u01, u2x) {                                              \
            float2 f01 = __half22float2(*reinterpret_cast<const __half2*>(&u01)); \
            float2 f2  = __half22float2(*reinterpret_cast<const __half2*>(&u2x)); \
            a[bi][0] = fmaf(sgn, f01.x, a[bi][0]);                                \
            a[bi][1] = fmaf(sgn, f01.y, a[bi][1]);                                \
            a[bi][2] = fmaf(sgn, f2.x,  a[bi][2]); }
        ACC_(0, q0.x, q0.y) ACC_(1, q0.z, q0.w)
        ACC_(2, q1.x, q1.y) ACC_(3, q1.z, q1.w)
        ACC_(4, q2.x, q2.y) ACC_(5, q2.z, q2.w)
        ACC_(6, q3.x, q3.y) ACC_(7, q3.z, q3.w)
        #undef ACC_
    }

    #pragma unroll
    for (int m = 32; m >= 1; m >>= 1) {
        #pragma unroll
        for (int b = 0; b < BB; b++) {
            a[b][0] += __shfl_xor(a[b][0], m);
            a[b][1] += __shfl_xor(a[b][1], m);
            a[b][2] += __shfl_xor(a[b][2], m);
        }
    }

    float bb0 = b3[0], bb1 = b3[1], bb2 = b3[2];
    #pragma unroll
    for (int b = 0; b < BB; b++) {
        if (lane == b) {
            float* o = out + ((size_t)b * N + node) * 3;
            o[0] = sigmoidf_(a[b][0] + bb0);
            o[1] = sigmoidf_(a[b][1] + bb1);
            o[2] = sigmoidf_(a[b][2] + bb2);
        }
    }
}

// ---- Fallback path (small ws or N > NBINS): scalar MLP + atomic scatter ----
__global__ void finalize_stats_kernel(const double* __restrict__ accp, int E,
                                      float* __restrict__ stats) {
    double s0 = 0, q0 = 0, s1 = 0, q1 = 0;
    for (int b = 0; b < NB; b++) {
        s0 += accp[4 * b + 0];
        q0 += accp[4 * b + 1];
        s1 += accp[4 * b + 2];
        q1 += accp[4 * b + 3];
    }
    double v0 = (q0 - s0 * s0 / E) / (double)(E - 1);
    double v1 = (q1 - s1 * s1 / E) / (double)(E - 1);
    stats[0] = (float)(s0 / E);
    stats[1] = (float)(1.0 / sqrt(v0));
    stats[2] = (float)(s1 / E);
    stats[3] = (float)(1.0 / sqrt(v1));
}

__device__ __forceinline__ void mlp_eval(
    const float feat[9],
    const float* __restrict__ W1, const float* __restrict__ b1,
    const float* __restrict__ W2, const float* __restrict__ b2,
    const float* __restrict__ W3,
    float& g0, float& g1, float& g2)
{
    const f32x2* W1p = (const f32x2*)W1;
    const f32x2* b1p = (const f32x2*)b1;
    f32x2 acc1[8];
    #pragma unroll
    for (int j = 0; j < 8; j++) acc1[j] = b1p[j];
    #pragma unroll
    for (int k = 0; k < 9; k++) {
        f32x2 fk2 = {feat[k], feat[k]};
        #pragma unroll
        for (int j = 0; j < 8; j++)
            acc1[j] = __builtin_elementwise_fma(fk2, W1p[k * 8 + j], acc1[j]);
    }
    float h1[16];
    #pragma unroll
    for (int j = 0; j < 8; j++) {
        h1[2 * j]     = sigmoidf_(acc1[j].x);
        h1[2 * j + 1] = sigmoidf_(acc1[j].y);
    }
    const f32x2* W2p = (const f32x2*)W2;
    const f32x2* b2p = (const f32x2*)b2;
    f32x2 acc2[15];
    #pragma unroll
    for (int k = 0; k < 15; k++) acc2[k] = b2p[k];
    #pragma unroll
    for (int j = 0; j < 16; j++) {
        f32x2 hj2 = {h1[j], h1[j]};
        #pragma unroll
        for (int k = 0; k < 15; k++)
            acc2[k] = __builtin_elementwise_fma(hj2, W2p[j * 15 + k], acc2[k]);
    }
    g0 = 0.f; g1 = 0.f; g2 = 0.f;
    #pragma unroll
    for (int k = 0; k < 15; k++) {
        float ha = sigmoidf_(acc2[k].x);
        float hb = sigmoidf_(acc2[k].y);
        int ka = 2 * k, kb = 2 * k + 1;
        g0 = fmaf(ha, W3[ka * 3 + 0], g0); g0 = fmaf(hb, W3[kb * 3 + 0], g0);
        g1 = fmaf(ha, W3[ka * 3 + 1], g1); g1 = fmaf(hb, W3[kb * 3 + 1], g1);
        g2 = fmaf(ha, W3[ka * 3 + 2], g2); g2 = fmaf(hb, W3[kb * 3 + 2], g2);
    }
}

__global__ __launch_bounds__(256) void edge_atomic_kernel(
    const float* __restrict__ x, const int* __restrict__ ei,
    const float* __restrict__ ea,
    const float* __restrict__ wmean, const float* __restrict__ wstd,
    const float* __restrict__ W1, const float* __restrict__ b1,
    const float* __restrict__ W2, const float* __restrict__ b2,
    const float* __restrict__ W3,
    const float* __restrict__ stats,
    float* __restrict__ out, int N, int E)
{
    int e = blockIdx.x * blockDim.x + threadIdx.x;
    if (e >= E) return;
    int src = ei[e];
    int tgt = ei[E + e];
    float dist = ea[2 * e];
    float cdir = ea[2 * e + 1];
    float ea0 = (dist - stats[0]) * stats[1];
    float ea1 = (cdir - stats[2]) * stats[3];

    for (int b = 0; b < BB; b++) {
        const float* xb = x + (size_t)b * N * 3;
        float s0 = xb[src * 3 + 0], s1 = xb[src * 3 + 1], s2 = xb[src * 3 + 2];
        float t0 = xb[tgt * 3 + 0], t1 = xb[tgt * 3 + 1], t2 = xb[tgt * 3 + 2];
        float speed = fmaf(s1, wstd[0], wmean[0]);
        float direc = fmaf(s2, wstd[1], wmean[1]);
        float theta = fabsf(cdir - direc);
        float ew = fmaxf(0.0f, speed * __cosf(theta) * 3.0f * __builtin_amdgcn_rcpf(dist));
        float feat[9] = {s0, s1, s2, t0, t1, t2, ea0, ea1, ew};
        float g0, g1, g2;
        mlp_eval(feat, W1, b1, W2, b2, W3, g0, g1, g2);
        float* ot = out + ((size_t)b * N + tgt) * 3;
        float* os = out + ((size_t)b * N + src) * 3;
        atomicAdd(&ot[0], g0);  atomicAdd(&ot[1], g1);  atomicAdd(&ot[2], g2);
        atomicAdd(&os[0], -g0); atomicAdd(&os[1], -g1); atomicAdd(&os[2], -g2);
    }
}

__global__ void output_kernel(float* __restrict__ out, const float* __restrict__ b3, int total) {
    int i = blockIdx.x * blockDim.x + threadIdx.x;
    if (i < total) out[i] = sigmoidf_(out[i] + b3[i % 3]);
}

extern "C" void kernel_launch(void* const* d_in, const int* in_sizes, int n_in,
                              void* d_out, int out_size, void* d_ws, size_t ws_size,
                              hipStream_t stream) {
    const float* x     = (const float*)d_in[0];
    const int*   ei    = (const int*)d_in[1];
    const float* ea    = (const float*)d_in[2];
    const float* wmean = (const float*)d_in[3];
    const float* wstd  = (const float*)d_in[4];
    const float* W1    = (const float*)d_in[5];
    const float* b1    = (const float*)d_in[6];
    const float* W2    = (const float*)d_in[7];
    const float* b2    = (const float*)d_in[8];
    const float* W3    = (const float*)d_in[9];
    const float* b3    = (const float*)d_in[10];

    int E = in_sizes[2] / 2;        // edge_attr is (E, 2)
    int N = in_sizes[0] / (BB * 3); // x is (B, N, 3)

    float* out = (float*)d_out;
    char* ws = (char*)d_ws;

    // layout: [accp NB*4 dbl][stats 4 f][tot NBINS][off N+1][list 2E][xT N*24 f][cnt2 NB*NBINS u16][gbuf E*8 uint2]
    double* accp  = (double*)ws;                       // NB*4 doubles = 4KB
    float*  stats = (float*)(ws + NB * 4 * sizeof(double));       // 16 B (+pad)
    int*    tot   = (int*)(ws + NB * 4 * sizeof(double) + 64);    // NBINS
    int*    off   = tot + NBINS;                       // N+1
    int*    list  = off + N + 1;                       // 2E

    size_t xtOff = NB * 4 * sizeof(double) + 64 +
                   sizeof(int) * ((size_t)NBINS + (N + 1) + 2 * (size_t)E);
    xtOff = (xtOff + 255) & ~(size_t)255;
    float* xT = (float*)(ws + xtOff);

    size_t c2Off = xtOff + (size_t)N * 24 * sizeof(float);
    c2Off = (c2Off + 255) & ~(size_t)255;
    unsigned short* cnt2 = (unsigned short*)(ws + c2Off);

    size_t gbOff = c2Off + (size_t)NB * NBINS * sizeof(unsigned short);
    gbOff = (gbOff + 255) & ~(size_t)255;
    uint2* gbuf = (uint2*)(ws + gbOff);
    size_t needed = gbOff + (size_t)E * BB * sizeof(uint2);

    int eblocks = (E + 255) / 256;
    int fastPath = (needed <= ws_size && N <= NBINS) ? 1 : 0;

    if (fastPath) {
        prep_kernel<<<NB, 256, 0, stream>>>(ea, ei, x, xT, cnt2, accp, N, E, 1);
        base_kernel<<<(NBINS + 255) / 256, 256, 0, stream>>>(cnt2, tot);
        scan_kernel<<<1, 1024, 0, stream>>>(tot, off, N, accp, E, stats);
        fused_rank_mlp_kernel<<<NB + 1920, 256, 0, stream>>>(
            xT, ei, ea, wmean, wstd, W1, b1, W2, b2, W3, stats,
            cnt2, off, list, gbuf, N, E);
        node_sum_kernel<<<(N + 3) / 4, 256, 0, stream>>>(
            gbuf, off, list, b3, out, N);
    } else {
        hipMemsetAsync(d_out, 0, (size_t)out_size * sizeof(float), stream);
        prep_kernel<<<NB, 256, 0, stream>>>(ea, ei, x, xT, cnt2, accp, N, E, 0);
        finalize_stats_kernel<<<1, 1, 0, stream>>>(accp, E, stats);
        edge_atomic_kernel<<<eblocks, 256, 0, stream>>>(
            x, ei, ea, wmean, wstd, W1, b1, W2, b2, W3, stats, out, N, E);
        output_kernel<<<(out_size + 255) / 256, 256, 0, stream>>>(out, b3, out_size);
    }
}

// Round 18
// 104.792 us; speedup vs baseline: 1.1511x; 1.0057x over previous
//
#include <hip/hip_runtime.h>
#include <hip/hip_fp16.h>
#include <math.h>

#define BB 8        // batch count (fixed by problem instance)
#define NB 128      // counting-sort blocks (chunk owners) == ranklist-role blocks
#define NBINS 10016 // padded bin count; fast path requires N <= NBINS
#define NBINSW 5008 // packed histogram words (2 u16 bins per u32)
#define FPAD 10     // fsh row stride in dwords (40B: conflict-free bank map)
#define SMEMW 5120  // union size in dwords: max(NBINSW, 4*2*64*FPAD)

typedef float f32x2 __attribute__((ext_vector_type(2)));
typedef float f32x4 __attribute__((ext_vector_type(4)));
typedef _Float16 h16x4 __attribute__((ext_vector_type(4)));

__device__ __forceinline__ float sigmoidf_(float v) {
    return __builtin_amdgcn_rcpf(1.0f + __expf(-v));
}
__device__ __forceinline__ float sigs_(float d) {   // pre-activation scaled by log2(e)
    return __builtin_amdgcn_rcpf(1.0f + __builtin_amdgcn_exp2f(-d));
}
__device__ __forceinline__ unsigned pkh2_(float a, float b) {
    __half2 h = __floats2half2_rn(a, b);
    return *reinterpret_cast<unsigned*>(&h);
}
// packed u16-bin histogram: bin b lives in half (b&1) of word (b>>1).
__device__ __forceinline__ unsigned hinc_(unsigned* hh, int b) {
    unsigned sh = (b & 1) * 16;
    unsigned old = atomicAdd(&hh[b >> 1], 1u << sh);
    return (old >> sh) & 0xFFFFu;
}

// ---- K1 prep: ea stats partials + xT transpose + packed LDS histogram -> cnt2 ----
__global__ __launch_bounds__(256) void prep_kernel(
    const float* __restrict__ ea, const int* __restrict__ ei,
    const float* __restrict__ x, float* __restrict__ xT,
    unsigned short* __restrict__ cnt2, double* __restrict__ accp,
    int N, int E, int full)
{
    __shared__ unsigned hh[NBINSW];
    __shared__ double sh[4][256];
    int tid = threadIdx.x;
    int blk = blockIdx.x;

    if (full) {
        for (int b = tid; b < NBINSW; b += 256) hh[b] = 0u;
    }

    double s0 = 0, q0 = 0, s1 = 0, q1 = 0;
    for (int i = blk * 256 + tid; i < E; i += NB * 256) {
        float a = ea[2 * i];
        float b = ea[2 * i + 1];
        s0 += (double)a; q0 += (double)a * (double)a;
        s1 += (double)b; q1 += (double)b * (double)b;
    }

    if (full) {
        int xtotal = N * BB * 3;
        for (int idx = blk * 256 + tid; idx < xtotal; idx += NB * 256) {
            int c = idx % 3;
            int rest = idx / 3;
            int n = rest % N;
            int b = rest / N;
            xT[n * 24 + b * 3 + c] = x[idx];
        }
        __syncthreads();
        int chunk = (E + NB - 1) / NB;
        int s = blk * chunk;
        int epd = min(E, s + chunk);
        for (int e = s + tid; e < epd; e += 256) {
            hinc_(hh, ei[E + e]);   // tgt (+g)
            hinc_(hh, ei[e]);       // src (-g)
        }
        __syncthreads();
        unsigned short* row = cnt2 + (size_t)blk * NBINS;
        for (int b = tid; b < NBINS; b += 256)
            row[b] = (unsigned short)((hh[b >> 1] >> ((b & 1) * 16)) & 0xFFFFu);
    }

    sh[0][tid] = s0; sh[1][tid] = q0; sh[2][tid] = s1; sh[3][tid] = q1;
    __syncthreads();
    for (int off = 128; off > 0; off >>= 1) {
        if (tid < off) {
            sh[0][tid] += sh[0][tid + off];
            sh[1][tid] += sh[1][tid + off];
            sh[2][tid] += sh[2][tid + off];
            sh[3][tid] += sh[3][tid + off];
        }
        __syncthreads();
    }
    if (tid == 0) {
        accp[4 * blk + 0] = sh[0][0];
        accp[4 * blk + 1] = sh[1][0];
        accp[4 * blk + 2] = sh[2][0];
        accp[4 * blk + 3] = sh[3][0];
    }
}

// ---- K2 base: per-bin exclusive prefix over blocks (in-place) + totals ----
__global__ __launch_bounds__(256) void base_kernel(unsigned short* __restrict__ cnt2,
                                                   int* __restrict__ tot) {
    int bin = blockIdx.x * 256 + threadIdx.x;
    if (bin >= NBINS) return;
    unsigned run = 0;
    #pragma unroll 8
    for (int blk = 0; blk < NB; blk++) {
        size_t idx = (size_t)blk * NBINS + bin;
        unsigned v = cnt2[idx];
        cnt2[idx] = (unsigned short)run;
        run += v;
    }
    tot[bin] = (int)run;
}

// ---- K3 scan: exclusive scan over node totals + stats finalize from partials ----
__global__ __launch_bounds__(1024) void scan_kernel(const int* __restrict__ tot,
                                                    int* __restrict__ off, int N,
                                                    const double* __restrict__ accp, int E,
                                                    float* __restrict__ stats) {
    if (threadIdx.x == 0) {
        double s0 = 0, q0 = 0, s1 = 0, q1 = 0;
        for (int b = 0; b < NB; b++) {
            s0 += accp[4 * b + 0];
            q0 += accp[4 * b + 1];
            s1 += accp[4 * b + 2];
            q1 += accp[4 * b + 3];
        }
        double v0 = (q0 - s0 * s0 / E) / (double)(E - 1);
        double v1 = (q1 - s1 * s1 / E) / (double)(E - 1);
        stats[0] = (float)(s0 / E);
        stats[1] = (float)(1.0 / sqrt(v0));
        stats[2] = (float)(s1 / E);
        stats[3] = (float)(1.0 / sqrt(v1));
    }
    __shared__ int sh[1024];
    int t = threadIdx.x;
    int chunk = (N + 1023) >> 10;
    int lo = t * chunk;
    int hi = lo + chunk; if (hi > N) hi = N;
    int s = 0;
    for (int i = lo; i < hi; i++) s += tot[i];
    sh[t] = s;
    __syncthreads();
    for (int d = 1; d < 1024; d <<= 1) {
        int v = (t >= d) ? sh[t - d] : 0;
        __syncthreads();
        sh[t] += v;
        __syncthreads();
    }
    int run = (t == 0) ? 0 : sh[t - 1];
    for (int i = lo; i < hi; i++) {
        off[i] = run;
        run += tot[i];
    }
    if (t == 1023) off[N] = sh[1023];
}

// ---- K4 (fused, role-split): ranklist (blocks 0..NB-1) ∥ MFMA MLP (rest) ----
// MLP role runs TWO independent group-chains (A/B) per iteration for 2x ILP:
// stash halves fsh[wave][2][64][FPAD]; tile loop interleaves both MFMA chains.
// NB: every LDS dword B1 reads (fp[0..7]) MUST be initialized — 0 x NaN = NaN.
__global__ __launch_bounds__(256) void fused_rank_mlp_kernel(
    const float* __restrict__ xT, const int* __restrict__ ei,
    const float* __restrict__ ea,
    const float* __restrict__ wmean, const float* __restrict__ wstd,
    const float* __restrict__ W1, const float* __restrict__ b1,
    const float* __restrict__ W2, const float* __restrict__ b2,
    const float* __restrict__ W3,
    const float* __restrict__ stats,
    const unsigned short* __restrict__ cnt2,
    const int* __restrict__ off, int* __restrict__ list,
    uint2* __restrict__ gbuf,
    int N, int E)
{
    __shared__ unsigned smem[SMEMW];   // union: packed hist / dual fsh
    int tid = threadIdx.x;

    if (blockIdx.x < NB) {
        // ---------------- ranklist role ----------------
        unsigned* hh = smem;
        int blk = blockIdx.x;
        for (int b = tid; b < NBINSW; b += 256) hh[b] = 0u;
        __syncthreads();
        int chunk = (E + NB - 1) / NB;
        int s = blk * chunk;
        int epd = min(E, s + chunk);
        const unsigned short* row = cnt2 + (size_t)blk * NBINS;
        for (int e = s + tid; e < epd; e += 256) {
            int tgt = ei[E + e];
            int src = ei[e];
            unsigned lt = hinc_(hh, tgt);
            unsigned ls = hinc_(hh, src);
            list[off[tgt] + (int)row[tgt] + (int)lt] = e;
            list[off[src] + (int)row[src] + (int)ls] = e | 0x80000000;
        }
        return;
    }

    // ---------------- MFMA MLP role (dual-chain ILP) ----------------
    typedef unsigned fsh_t[2][64][FPAD];
    fsh_t* fsh = reinterpret_cast<fsh_t*>(smem);   // [wave][half][pair][FPAD]

    int mlp_id = blockIdx.x - NB;
    int nmlp = gridDim.x - NB;
    int lane = tid & 63;
    int wave = tid >> 6;
    int g = lane >> 4;        // k-group / row-group
    int arow = lane & 15;     // A row / D col

    const float LOG2E = 1.44269504088896340736f;

    float st0 = stats[0], st1 = stats[1], st2 = stats[2], st3 = stats[3];

    // preload weight fragments (constant across steps)
    h16x4 A1, A2a, A2b, A3a, A3b;
    #pragma unroll
    for (int j = 0; j < 4; j++) {
        int k = 4 * g + j;
        A1[j]  = (_Float16)((k < 9) ? W1[k * 16 + arow] * LOG2E : 0.0f);
        A2a[j] = (_Float16)(W2[k * 30 + arow] * LOG2E);
        A2b[j] = (_Float16)((arow < 14) ? W2[k * 30 + 16 + arow] * LOG2E : 0.0f);
        A3a[j] = (_Float16)((arow < 3) ? W3[k * 3 + arow] : 0.0f);
        int k2 = 16 + k;
        A3b[j] = (_Float16)((arow < 3 && k2 < 30) ? W3[k2 * 3 + arow] : 0.0f);
    }
    f32x4 C1, C2a, C2b;
    #pragma unroll
    for (int r = 0; r < 4; r++) {
        int row = 4 * g + r;
        C1[r]  = b1[row] * LOG2E;
        C2a[r] = b2[row] * LOG2E;
        C2b[r] = (row < 14) ? b2[16 + row] * LOG2E : 0.0f;
    }

    float wm0 = wmean[0], wm1 = wmean[1];
    float wsd0 = wstd[0], wsd1 = wstd[1];

    int e_loc = lane >> 3;    // 0..7 : edge within step
    int bb = lane & 7;        // 0..7 : batch

    // compute features for one (edge,batch) pair and stash to given half
    auto feat_stash = [&](int ebase, int half) {
        int e = ebase + e_loc;
        int esafe = (e < E) ? e : (E - 1);
        int src = ei[esafe];
        int tgt = ei[E + esafe];
        float dist = ea[2 * esafe];
        float cdir = ea[2 * esafe + 1];
        const float* xs = xT + src * 24 + bb * 3;
        const float* xt = xT + tgt * 24 + bb * 3;
        float s0 = xs[0], s1 = xs[1], s2 = xs[2];
        float t0 = xt[0], t1 = xt[1], t2 = xt[2];
        float ea0 = (dist - st0) * st1;
        float ea1 = (cdir - st2) * st3;
        float speed = fmaf(s1, wsd0, wm0);
        float direc = fmaf(s2, wsd1, wm1);
        float theta = fabsf(cdir - direc);
        float ew = fmaxf(0.0f, speed * __cosf(theta) * 3.0f * __builtin_amdgcn_rcpf(dist));
        unsigned* fp = &fsh[wave][half][lane][0];
        uint4 wv0, wv1;
        wv0.x = pkh2_(s0, s1); wv0.y = pkh2_(s2, t0);
        wv0.z = pkh2_(t1, t2); wv0.w = pkh2_(ea0, ea1);
        wv1.x = pkh2_(ew, 0.0f); wv1.y = 0u; wv1.z = 0u; wv1.w = 0u;
        *reinterpret_cast<uint4*>(fp) = wv0;
        *reinterpret_cast<uint4*>(fp + 4) = wv1;
    };

    int ngrp = (E + 31) >> 5;          // 32-edge groups
    int half = (ngrp + 1) >> 1;        // chain A: [0,half), chain B: [half,2*half)

    for (int gA = mlp_id; gA < half; gA += nmlp) {
        int gB = gA + half;
        int ebA = gA * 32 + wave * 8;
        int ebB = gB * 32 + wave * 8;   // may exceed E on tail -> guarded at store

        feat_stash(ebA, 0);
        feat_stash(ebB, 1);

        #pragma unroll
        for (int t = 0; t < 4; t++) {
            const unsigned* qA = &fsh[wave][0][t * 16 + arow][0];
            const unsigned* qB = &fsh[wave][1][t * 16 + arow][0];
            union { uint2 u; h16x4 h; } b1A, b1B;
            b1A.u = *reinterpret_cast<const uint2*>(qA + 2 * g);
            b1B.u = *reinterpret_cast<const uint2*>(qB + 2 * g);

            f32x4 D1A = __builtin_amdgcn_mfma_f32_16x16x16f16(A1, b1A.h, C1, 0, 0, 0);
            f32x4 D1B = __builtin_amdgcn_mfma_f32_16x16x16f16(A1, b1B.h, C1, 0, 0, 0);
            union { uint2 u; h16x4 h; } b2A, b2B;
            b2A.u.x = pkh2_(sigs_(D1A[0]), sigs_(D1A[1]));
            b2A.u.y = pkh2_(sigs_(D1A[2]), sigs_(D1A[3]));
            b2B.u.x = pkh2_(sigs_(D1B[0]), sigs_(D1B[1]));
            b2B.u.y = pkh2_(sigs_(D1B[2]), sigs_(D1B[3]));

            f32x4 D2aA = __builtin_amdgcn_mfma_f32_16x16x16f16(A2a, b2A.h, C2a, 0, 0, 0);
            f32x4 D2aB = __builtin_amdgcn_mfma_f32_16x16x16f16(A2a, b2B.h, C2a, 0, 0, 0);
            f32x4 D2bA = __builtin_amdgcn_mfma_f32_16x16x16f16(A2b, b2A.h, C2b, 0, 0, 0);
            f32x4 D2bB = __builtin_amdgcn_mfma_f32_16x16x16f16(A2b, b2B.h, C2b, 0, 0, 0);
            union { uint2 u; h16x4 h; } b3aA, b3bA, b3aB, b3bB;
            b3aA.u.x = pkh2_(sigs_(D2aA[0]), sigs_(D2aA[1]));
            b3aA.u.y = pkh2_(sigs_(D2aA[2]), sigs_(D2aA[3]));
            b3bA.u.x = pkh2_(sigs_(D2bA[0]), sigs_(D2bA[1]));
            b3bA.u.y = pkh2_(sigs_(D2bA[2]), sigs_(D2bA[3]));
            b3aB.u.x = pkh2_(sigs_(D2aB[0]), sigs_(D2aB[1]));
            b3aB.u.y = pkh2_(sigs_(D2aB[2]), sigs_(D2aB[3]));
            b3bB.u.x = pkh2_(sigs_(D2bB[0]), sigs_(D2bB[1]));
            b3bB.u.y = pkh2_(sigs_(D2bB[2]), sigs_(D2bB[3]));

            f32x4 Z = {0.f, 0.f, 0.f, 0.f};
            f32x4 D3A = __builtin_amdgcn_mfma_f32_16x16x16f16(A3a, b3aA.h, Z, 0, 0, 0);
            f32x4 D3B = __builtin_amdgcn_mfma_f32_16x16x16f16(A3a, b3aB.h, Z, 0, 0, 0);
            D3A = __builtin_amdgcn_mfma_f32_16x16x16f16(A3b, b3bA.h, D3A, 0, 0, 0);
            D3B = __builtin_amdgcn_mfma_f32_16x16x16f16(A3b, b3bB.h, D3B, 0, 0, 0);

            if (g == 0) {
                int bt = arow & 7;                      // batch of this col
                int etA = ebA + 2 * t + (arow >> 3);    // edge of this col
                int etB = ebB + 2 * t + (arow >> 3);
                if (etA < E) {
                    uint2 wp;
                    wp.x = pkh2_(D3A[0], D3A[1]);
                    wp.y = pkh2_(D3A[2], 0.0f);
                    gbuf[(size_t)etA * BB + bt] = wp;
                }
                if (etB < E) {
                    uint2 wp;
                    wp.x = pkh2_(D3B[0], D3B[1]);
                    wp.y = pkh2_(D3B[2], 0.0f);
                    gbuf[(size_t)etB * BB + bt] = wp;
                }
            }
        }
    }
}

// ---- K5: one wave per node; each lane consumes one full 64B edge-line ----
__global__ __launch_bounds__(256) void node_sum_kernel(
    const uint2* __restrict__ gbuf, const int* __restrict__ off,
    const int* __restrict__ list,
    const float* __restrict__ b3, float* __restrict__ out, int N)
{
    int node = blockIdx.x * 4 + (threadIdx.x >> 6);
    int lane = threadIdx.x & 63;
    if (node >= N) return;

    int o0 = off[node], o1 = off[node + 1];
    float a[BB][3];
    #pragma unroll
    for (int b = 0; b < BB; b++) { a[b][0] = 0.f; a[b][1] = 0.f; a[b][2] = 0.f; }

    for (int i = o0 + lane; i < o1; i += 64) {
        int entry = list[i];
        int e = entry & 0x7FFFFFFF;
        float sgn = (entry < 0) ? -1.0f : 1.0f;
        const uint4* gl = reinterpret_cast<const uint4*>(gbuf + (size_t)e * BB);
        uint4 q0 = gl[0], q1 = gl[1], q2 = gl[2], q3 = gl[3];

        #define ACC_(bi, u01, u2x) {                                              \
            float2 f01 = __half22float2(*reinterpret_cast<const __half2*>(&u01)); \
            float2 f2  = __half22float2(*reinterpret_cast<const __half2*>(&u2x)); \
            a[bi][0] = fmaf(sgn, f01.x, a[bi][0]);                                \
            a[bi][1] = fmaf(sgn, f01.y, a[bi][1]);                                \
            a[bi][2] = fmaf(sgn, f2.x,  a[bi][2]); }
        ACC_(0, q0.x, q0.y) ACC_(1, q0.z, q0.w)
        ACC_(2, q1.x, q1.y) ACC_(3, q1.z, q1.w)
        ACC_(4, q2.x, q2.y) ACC_(5, q2.z, q2.w)
        ACC_(6, q3.x, q3.y) ACC_(7, q3.z, q3.w)
        #undef ACC_
    }

    #pragma unroll
    for (int m = 32; m >= 1; m >>= 1) {
        #pragma unroll
        for (int b = 0; b < BB; b++) {
            a[b][0] += __shfl_xor(a[b][0], m);
            a[b][1] += __shfl_xor(a[b][1], m);
            a[b][2] += __shfl_xor(a[b][2], m);
        }
    }

    float bb0 = b3[0], bb1 = b3[1], bb2 = b3[2];
    #pragma unroll
    for (int b = 0; b < BB; b++) {
        if (lane == b) {
            float* o = out + ((size_t)b * N + node) * 3;
            o[0] = sigmoidf_(a[b][0] + bb0);
            o[1] = sigmoidf_(a[b][1] + bb1);
            o[2] = sigmoidf_(a[b][2] + bb2);
        }
    }
}

// ---- Fallback path (small ws or N > NBINS): scalar MLP + atomic scatter ----
__global__ void finalize_stats_kernel(const double* __restrict__ accp, int E,
                                      float* __restrict__ stats) {
    double s0 = 0, q0 = 0, s1 = 0, q1 = 0;
    for (int b = 0; b < NB; b++) {
        s0 += accp[4 * b + 0];
        q0 += accp[4 * b + 1];
        s1 += accp[4 * b + 2];
        q1 += accp[4 * b + 3];
    }
    double v0 = (q0 - s0 * s0 / E) / (double)(E - 1);
    double v1 = (q1 - s1 * s1 / E) / (double)(E - 1);
    stats[0] = (float)(s0 / E);
    stats[1] = (float)(1.0 / sqrt(v0));
    stats[2] = (float)(s1 / E);
    stats[3] = (float)(1.0 / sqrt(v1));
}

__device__ __forceinline__ void mlp_eval(
    const float feat[9],
    const float* __restrict__ W1, const float* __restrict__ b1,
    const float* __restrict__ W2, const float* __restrict__ b2,
    const float* __restrict__ W3,
    float& g0, float& g1, float& g2)
{
    const f32x2* W1p = (const f32x2*)W1;
    const f32x2* b1p = (const f32x2*)b1;
    f32x2 acc1[8];
    #pragma unroll
    for (int j = 0; j < 8; j++) acc1[j] = b1p[j];
    #pragma unroll
    for (int k = 0; k < 9; k++) {
        f32x2 fk2 = {feat[k], feat[k]};
        #pragma unroll
        for (int j = 0; j < 8; j++)
            acc1[j] = __builtin_elementwise_fma(fk2, W1p[k * 8 + j], acc1[j]);
    }
    float h1[16];
    #pragma unroll
    for (int j = 0; j < 8; j++) {
        h1[2 * j]     = sigmoidf_(acc1[j].x);
        h1[2 * j + 1] = sigmoidf_(acc1[j].y);
    }
    const f32x2* W2p = (const f32x2*)W2;
    const f32x2* b2p = (const f32x2*)b2;
    f32x2 acc2[15];
    #pragma unroll
    for (int k = 0; k < 15; k++) acc2[k] = b2p[k];
    #pragma unroll
    for (int j = 0; j < 16; j++) {
        f32x2 hj2 = {h1[j], h1[j]};
        #pragma unroll
        for (int k = 0; k < 15; k++)
            acc2[k] = __builtin_elementwise_fma(hj2, W2p[j * 15 + k], acc2[k]);
    }
    g0 = 0.f; g1 = 0.f; g2 = 0.f;
    #pragma unroll
    for (int k = 0; k < 15; k++) {
        float ha = sigmoidf_(acc2[k].x);
        float hb = sigmoidf_(acc2[k].y);
        int ka = 2 * k, kb = 2 * k + 1;
        g0 = fmaf(ha, W3[ka * 3 + 0], g0); g0 = fmaf(hb, W3[kb * 3 + 0], g0);
        g1 = fmaf(ha, W3[ka * 3 + 1], g1); g1 = fmaf(hb, W3[kb * 3 + 1], g1);
        g2 = fmaf(ha, W3[ka * 3 + 2], g2); g2 = fmaf(hb, W3[kb * 3 + 2], g2);
    }
}

__global__ __launch_bounds__(256) void edge_atomic_kernel(
    const float* __restrict__ x, const int* __restrict__ ei,
    const float* __restrict__ ea,
    const float* __restrict__ wmean, const float* __restrict__ wstd,
    const float* __restrict__ W1, const float* __restrict__ b1,
    const float* __restrict__ W2, const float* __restrict__ b2,
    const float* __restrict__ W3,
    const float* __restrict__ stats,
    float* __restrict__ out, int N, int E)
{
    int e = blockIdx.x * blockDim.x + threadIdx.x;
    if (e >= E) return;
    int src = ei[e];
    int tgt = ei[E + e];
    float dist = ea[2 * e];
    float cdir = ea[2 * e + 1];
    float ea0 = (dist - stats[0]) * stats[1];
    float ea1 = (cdir - stats[2]) * stats[3];

    for (int b = 0; b < BB; b++) {
        const float* xb = x + (size_t)b * N * 3;
        float s0 = xb[src * 3 + 0], s1 = xb[src * 3 + 1], s2 = xb[src * 3 + 2];
        float t0 = xb[tgt * 3 + 0], t1 = xb[tgt * 3 + 1], t2 = xb[tgt * 3 + 2];
        float speed = fmaf(s1, wstd[0], wmean[0]);
        float direc = fmaf(s2, wstd[1], wmean[1]);
        float theta = fabsf(cdir - direc);
        float ew = fmaxf(0.0f, speed * __cosf(theta) * 3.0f * __builtin_amdgcn_rcpf(dist));
        float feat[9] = {s0, s1, s2, t0, t1, t2, ea0, ea1, ew};
        float g0, g1, g2;
        mlp_eval(feat, W1, b1, W2, b2, W3, g0, g1, g2);
        float* ot = out + ((size_t)b * N + tgt) * 3;
        float* os = out + ((size_t)b * N + src) * 3;
        atomicAdd(&ot[0], g0);  atomicAdd(&ot[1], g1);  atomicAdd(&ot[2], g2);
        atomicAdd(&os[0], -g0); atomicAdd(&os[1], -g1); atomicAdd(&os[2], -g2);
    }
}

__global__ void output_kernel(float* __restrict__ out, const float* __restrict__ b3, int total) {
    int i = blockIdx.x * blockDim.x + threadIdx.x;
    if (i < total) out[i] = sigmoidf_(out[i] + b3[i % 3]);
}

extern "C" void kernel_launch(void* const* d_in, const int* in_sizes, int n_in,
                              void* d_out, int out_size, void* d_ws, size_t ws_size,
                              hipStream_t stream) {
    const float* x     = (const float*)d_in[0];
    const int*   ei    = (const int*)d_in[1];
    const float* ea    = (const float*)d_in[2];
    const float* wmean = (const float*)d_in[3];
    const float* wstd  = (const float*)d_in[4];
    const float* W1    = (const float*)d_in[5];
    const float* b1    = (const float*)d_in[6];
    const float* W2    = (const float*)d_in[7];
    const float* b2    = (const float*)d_in[8];
    const float* W3    = (const float*)d_in[9];
    const float* b3    = (const float*)d_in[10];

    int E = in_sizes[2] / 2;        // edge_attr is (E, 2)
    int N = in_sizes[0] / (BB * 3); // x is (B, N, 3)

    float* out = (float*)d_out;
    char* ws = (char*)d_ws;

    // layout: [accp NB*4 dbl][stats 4 f][tot NBINS][off N+1][list 2E][xT N*24 f][cnt2 NB*NBINS u16][gbuf E*8 uint2]
    double* accp  = (double*)ws;                       // NB*4 doubles = 4KB
    float*  stats = (float*)(ws + NB * 4 * sizeof(double));       // 16 B (+pad)
    int*    tot   = (int*)(ws + NB * 4 * sizeof(double) + 64);    // NBINS
    int*    off   = tot + NBINS;                       // N+1
    int*    list  = off + N + 1;                       // 2E

    size_t xtOff = NB * 4 * sizeof(double) + 64 +
                   sizeof(int) * ((size_t)NBINS + (N + 1) + 2 * (size_t)E);
    xtOff = (xtOff + 255) & ~(size_t)255;
    float* xT = (float*)(ws + xtOff);

    size_t c2Off = xtOff + (size_t)N * 24 * sizeof(float);
    c2Off = (c2Off + 255) & ~(size_t)255;
    unsigned short* cnt2 = (unsigned short*)(ws + c2Off);

    size_t gbOff = c2Off + (size_t)NB * NBINS * sizeof(unsigned short);
    gbOff = (gbOff + 255) & ~(size_t)255;
    uint2* gbuf = (uint2*)(ws + gbOff);
    size_t needed = gbOff + (size_t)E * BB * sizeof(uint2);

    int eblocks = (E + 255) / 256;
    int fastPath = (needed <= ws_size && N <= NBINS) ? 1 : 0;

    if (fastPath) {
        prep_kernel<<<NB, 256, 0, stream>>>(ea, ei, x, xT, cnt2, accp, N, E, 1);
        base_kernel<<<(NBINS + 255) / 256, 256, 0, stream>>>(cnt2, tot);
        scan_kernel<<<1, 1024, 0, stream>>>(tot, off, N, accp, E, stats);
        fused_rank_mlp_kernel<<<NB + 1920, 256, 0, stream>>>(
            xT, ei, ea, wmean, wstd, W1, b1, W2, b2, W3, stats,
            cnt2, off, list, gbuf, N, E);
        node_sum_kernel<<<(N + 3) / 4, 256, 0, stream>>>(
            gbuf, off, list, b3, out, N);
    } else {
        hipMemsetAsync(d_out, 0, (size_t)out_size * sizeof(float), stream);
        prep_kernel<<<NB, 256, 0, stream>>>(ea, ei, x, xT, cnt2, accp, N, E, 0);
        finalize_stats_kernel<<<1, 1, 0, stream>>>(accp, E, stats);
        edge_atomic_kernel<<<eblocks, 256, 0, stream>>>(
            x, ei, ea, wmean, wstd, W1, b1, W2, b2, W3, stats, out, N, E);
        output_kernel<<<(out_size + 255) / 256, 256, 0, stream>>>(out, b3, out_size);
    }
}